// Round 7
// baseline (754.271 us; speedup 1.0000x reference)
//
#include <hip/hip_runtime.h>
#include <hip/hip_bf16.h>
#include <math.h>

typedef __hip_bfloat16 bf16;
typedef __attribute__((ext_vector_type(8))) short short8;
typedef __attribute__((ext_vector_type(4))) short short4v;
typedef __attribute__((ext_vector_type(4))) unsigned short ushort4v;
typedef __attribute__((ext_vector_type(4))) float f32x4;

#define BB 8
#define CC 256
#define NTOKB 4096          // tokens per batch (64*64)
#define FF 256
#define HIDDEN 1024
#define GBATCH 4            // batches per group (fast path)
#define GROWS (GBATCH*NTOKB)   // 16384 rows per group

__device__ __forceinline__ float bf2f(bf16 x) { return __bfloat162float(x); }
__device__ __forceinline__ bf16 f2bf(float x) { return __float2bfloat16(x); }
__device__ __forceinline__ float clampf(float v, float lo, float hi) {
    return fminf(fmaxf(v, lo), hi);
}
__device__ __forceinline__ float s2f(short s) {
    unsigned int u = ((unsigned int)(unsigned short)s) << 16;
    float f; __builtin_memcpy(&f, &u, 4); return f;
}
__device__ __forceinline__ unsigned short f2bits(float v) {
    bf16 h = f2bf(v);
    unsigned short b; __builtin_memcpy(&b, &h, 2); return b;
}

// mode-aware sanitized load for EXTERNAL inputs. mode=1: fp32; mode=0: bf16.
__device__ __forceinline__ float ldin(const void* p, size_t i, int fp32mode) {
    float v = fp32mode ? ((const float*)p)[i] : __bfloat162float(((const bf16*)p)[i]);
    if (!(v == v)) v = 0.f;
    return clampf(v, -1e4f, 1e4f);
}

__device__ __forceinline__ float wave_sum(float v) {
#pragma unroll
    for (int off = 32; off > 0; off >>= 1) v += __shfl_xor(v, off, 64);
    return v;
}

// ---------------- dtype detector ----------------
__global__ void detect_mode(const void* __restrict__ x, int* __restrict__ flag) {
    int i = threadIdx.x;
    float vb = __bfloat162float(((const bf16*)x)[(size_t)i * 37 + 1]);
    int bad = (!(vb == vb)) || (fabsf(vb) > 1e4f);
    unsigned long long m = __ballot(bad);
    if (i == 0) *flag = (m != 0ull) ? 1 : 0;
}

// ============================================================================
//                     SHARED SMALL KERNELS
// ============================================================================

__global__ void transpose_in_off(const void* __restrict__ X, bf16* __restrict__ T,
                                 const int* __restrict__ mode, size_t eoff) {
    __shared__ float tile[32][33];
    int fp32 = *mode;
    int n0 = blockIdx.x * 32, c0 = blockIdx.y * 32;
    int tx = threadIdx.x, ty = threadIdx.y;   // 32 x 8
    for (int i = ty; i < 32; i += 8)
        tile[i][tx] = ldin(X, eoff + (size_t)(c0 + i) * NTOKB + n0 + tx, fp32);
    __syncthreads();
    for (int i = ty; i < 32; i += 8)
        T[(size_t)(n0 + i) * CC + c0 + tx] = f2bf(tile[tx][i]);
}

__global__ void transpose_out_off(const bf16* __restrict__ T, void* __restrict__ O,
                                  const int* __restrict__ mode, size_t eoff) {
    __shared__ float tile[32][33];
    int fp32 = *mode;
    int c0 = blockIdx.x * 32, n0 = blockIdx.y * 32;
    int tx = threadIdx.x, ty = threadIdx.y;   // 32 x 8
    for (int i = ty; i < 32; i += 8)
        tile[i][tx] = bf2f(T[(size_t)(n0 + i) * CC + c0 + tx]);
    __syncthreads();
    for (int i = ty; i < 32; i += 8) {
        size_t idx = eoff + (size_t)(c0 + i) * NTOKB + n0 + tx;
        float v = tile[tx][i];
        if (fp32) ((float*)O)[idx] = v; else ((bf16*)O)[idx] = f2bf(v);
    }
}

__global__ void transpose_in_z(const void* __restrict__ X, bf16* __restrict__ T,
                               const int* __restrict__ mode) {
    __shared__ float tile[32][33];
    int fp32 = *mode;
    int b = blockIdx.z;
    int n0 = blockIdx.x * 32, c0 = blockIdx.y * 32;
    int tx = threadIdx.x, ty = threadIdx.y;
    size_t eoff = (size_t)b * CC * NTOKB;
    for (int i = ty; i < 32; i += 8)
        tile[i][tx] = ldin(X, eoff + (size_t)(c0 + i) * NTOKB + n0 + tx, fp32);
    __syncthreads();
    for (int i = ty; i < 32; i += 8)
        T[((size_t)b * NTOKB + n0 + i) * CC + c0 + tx] = f2bf(tile[tx][i]);
}

__global__ void transpose_out_z(const bf16* __restrict__ T, void* __restrict__ O,
                                const int* __restrict__ mode) {
    __shared__ float tile[32][33];
    int fp32 = *mode;
    int b = blockIdx.z;
    int c0 = blockIdx.x * 32, n0 = blockIdx.y * 32;
    int tx = threadIdx.x, ty = threadIdx.y;
    for (int i = ty; i < 32; i += 8)
        tile[i][tx] = bf2f(T[((size_t)b * NTOKB + n0 + i) * CC + c0 + tx]);
    __syncthreads();
    for (int i = ty; i < 32; i += 8) {
        size_t idx = (size_t)b * CC * NTOKB + (size_t)(c0 + i) * NTOKB + n0 + tx;
        float v = tile[tx][i];
        if (fp32) ((float*)O)[idx] = v; else ((bf16*)O)[idx] = f2bf(v);
    }
}

// scalar layernorm (fallback path)
__global__ void layernorm_k(const bf16* __restrict__ X, const void* __restrict__ g,
                            const void* __restrict__ bta, bf16* __restrict__ Y,
                            const int* __restrict__ mode) {
    int fp32 = *mode;
    int t = blockIdx.x * 4 + (threadIdx.x >> 6);
    int lane = threadIdx.x & 63;
    const bf16* row = X + (size_t)t * CC;
    float v[4], s = 0.f, s2 = 0.f;
#pragma unroll
    for (int j = 0; j < 4; j++) {
        v[j] = bf2f(row[lane + 64 * j]);
        s += v[j]; s2 += v[j] * v[j];
    }
    s = wave_sum(s); s2 = wave_sum(s2);
    float mu = s * (1.f / CC);
    float var = s2 * (1.f / CC) - mu * mu;
    float rstd = rsqrtf(fmaxf(var, 0.f) + 1e-5f);
    bf16* yrow = Y + (size_t)t * CC;
#pragma unroll
    for (int j = 0; j < 4; j++) {
        int c = lane + 64 * j;
        yrow[c] = f2bf((v[j] - mu) * rstd * ldin(g, c, fp32) + ldin(bta, c, fp32));
    }
}

// vectorized layernorm (fast path): lane handles 4 contiguous channels
__global__ void layernorm_v(const bf16* __restrict__ X, const void* __restrict__ g,
                            const void* __restrict__ bta, bf16* __restrict__ Y,
                            const int* __restrict__ mode) {
    int fp32 = *mode;
    int t = blockIdx.x * 4 + (threadIdx.x >> 6);
    int lane = threadIdx.x & 63;
    const short* row = (const short*)X + (size_t)t * CC;
    short4v u = *(const short4v*)&row[lane * 4];
    float v[4], s = 0.f, s2 = 0.f;
#pragma unroll
    for (int j = 0; j < 4; j++) { v[j] = s2f(u[j]); s += v[j]; s2 += v[j] * v[j]; }
    s = wave_sum(s); s2 = wave_sum(s2);
    float mu = s * (1.f / CC);
    float var = s2 * (1.f / CC) - mu * mu;
    float rstd = rsqrtf(fmaxf(var, 0.f) + 1e-5f);
    ushort4v o;
#pragma unroll
    for (int j = 0; j < 4; j++) {
        int c = lane * 4 + j;
        o[j] = f2bits((v[j] - mu) * rstd * ldin(g, c, fp32) + ldin(bta, c, fp32));
    }
    *(ushort4v*)((unsigned short*)Y + (size_t)t * CC + lane * 4) = o;
}

// scalar rownorm (fallback)
__global__ void rownorm_k(bf16* __restrict__ Q, float* __restrict__ DIAG) {
    int t = blockIdx.x * 4 + (threadIdx.x >> 6);
    int lane = threadIdx.x & 63;
    bf16* row = Q + (size_t)t * CC;
    float v[4], s2 = 0.f;
#pragma unroll
    for (int j = 0; j < 4; j++) { v[j] = bf2f(row[lane + 64 * j]); s2 += v[j] * v[j]; }
    s2 = wave_sum(s2);
    float nrm = sqrtf(fmaxf(s2, 0.f));
    float scale = 1.f / fmaxf(nrm, 5e-5f);
#pragma unroll
    for (int j = 0; j < 4; j++) row[lane + 64 * j] = f2bf(v[j] * scale);
    if (lane == 0) DIAG[t] = 0.5f * s2 * scale * scale;
}

// vectorized rownorm (fast path)
__global__ void rownorm_v(bf16* __restrict__ Q, float* __restrict__ DIAG) {
    int t = blockIdx.x * 4 + (threadIdx.x >> 6);
    int lane = threadIdx.x & 63;
    short* row = (short*)Q + (size_t)t * CC;
    short4v u = *(const short4v*)&row[lane * 4];
    float v[4], s2 = 0.f;
#pragma unroll
    for (int j = 0; j < 4; j++) { v[j] = s2f(u[j]); s2 += v[j] * v[j]; }
    s2 = wave_sum(s2);
    float nrm = sqrtf(fmaxf(s2, 0.f));
    float scale = 1.f / fmaxf(nrm, 5e-5f);
    ushort4v o;
#pragma unroll
    for (int j = 0; j < 4; j++) o[j] = f2bits(v[j] * scale);
    *(ushort4v*)&row[lane * 4] = o;
    if (lane == 0) DIAG[t] = 0.5f * s2 * scale * scale;
}

// ============================================================================
//                     FALLBACK (R5) GEMM KERNELS — proven path
// ============================================================================

template <int EPI>
__global__ void gemm_nt(const bf16* __restrict__ A, const void* __restrict__ Bw,
                        const void* __restrict__ bias, const float* __restrict__ diag,
                        const bf16* __restrict__ resid, bf16* __restrict__ Cm,
                        int M, int Nn, int Kk, const int* __restrict__ mode) {
    __shared__ float As[32][33];
    __shared__ float Bs[32][33];
    int fp32 = *mode;
    int tx = threadIdx.x, ty = threadIdx.y;
    int n0 = blockIdx.x * 32, m0 = blockIdx.y * 32;
    int tid = ty * 16 + tx;
    int lr = tid >> 5, lc = tid & 31;
    float acc[2][2] = {{0.f, 0.f}, {0.f, 0.f}};
    for (int k0 = 0; k0 < Kk; k0 += 32) {
#pragma unroll
        for (int i = 0; i < 4; i++) {
            int r = lr + 8 * i;
            As[r][lc] = bf2f(A[(size_t)(m0 + r) * Kk + k0 + lc]);
            Bs[r][lc] = ldin(Bw, (size_t)(n0 + r) * Kk + k0 + lc, fp32);
        }
        __syncthreads();
#pragma unroll
        for (int kk = 0; kk < 32; kk++) {
            float a0 = As[ty][kk], a1 = As[ty + 16][kk];
            float b0 = Bs[tx][kk], b1 = Bs[tx + 16][kk];
            acc[0][0] += a0 * b0; acc[0][1] += a0 * b1;
            acc[1][0] += a1 * b0; acc[1][1] += a1 * b1;
        }
        __syncthreads();
    }
#pragma unroll
    for (int i = 0; i < 2; i++)
#pragma unroll
        for (int j = 0; j < 2; j++) {
            int m = m0 + ty + 16 * i, n = n0 + tx + 16 * j;
            float v = acc[i][j];
            if (EPI == 0) {
                v = clampf(v + ldin(bias, n, fp32), -1e6f, 1e6f);
            } else if (EPI == 1) {
                v = fminf(0.0625f * (expf(fminf(v - diag[m], 60.f)) + 1e-4f), 1e8f);
            } else if (EPI == 2) {
                v += ldin(bias, n, fp32);
                v = 0.5f * v * (1.f + erff(v * 0.70710678118654752f));
            } else if (EPI == 3) {
                v += ldin(bias, n, fp32);
                v = clampf(v + bf2f(resid[(size_t)m * Nn + n]), -1e6f, 1e6f);
            }
            Cm[(size_t)m * Nn + n] = f2bf(v);
        }
}

__global__ void gemm_ctx_fb(const bf16* __restrict__ KP, const bf16* __restrict__ V,
                            float* __restrict__ CTX) {
    __shared__ float Ks[32][33];
    __shared__ float Vs[32][33];
    int c0 = blockIdx.x * 32, f0 = blockIdx.y * 32;
    int tx = threadIdx.x, ty = threadIdx.y;
    int tid = ty * 16 + tx, lr = tid >> 5, lc = tid & 31;
    float acc[2][2] = {{0.f, 0.f}, {0.f, 0.f}};
    for (int n0 = 0; n0 < NTOKB; n0 += 32) {
#pragma unroll
        for (int i = 0; i < 4; i++) {
            int r = lr + 8 * i;
            Ks[r][lc] = bf2f(KP[(size_t)(n0 + r) * FF + f0 + lc]);
            Vs[r][lc] = bf2f(V[(size_t)(n0 + r) * CC + c0 + lc]);
        }
        __syncthreads();
#pragma unroll
        for (int kk = 0; kk < 32; kk++) {
            float a0 = Ks[kk][ty], a1 = Ks[kk][ty + 16];
            float b0 = Vs[kk][tx], b1 = Vs[kk][tx + 16];
            acc[0][0] += a0 * b0; acc[0][1] += a0 * b1;
            acc[1][0] += a1 * b0; acc[1][1] += a1 * b1;
        }
        __syncthreads();
    }
#pragma unroll
    for (int i = 0; i < 2; i++)
#pragma unroll
        for (int j = 0; j < 2; j++)
            CTX[(size_t)(f0 + ty + 16 * i) * CC + c0 + tx + 16 * j] =
                clampf(acc[i][j], -1e18f, 1e18f);
}

__global__ void gemm_attnout_fb(const bf16* __restrict__ QP, const float* __restrict__ CTX,
                                const float* __restrict__ DINV, bf16* __restrict__ T) {
    __shared__ float As[32][33];
    __shared__ float Bs[32][33];
    int c0 = blockIdx.x * 32, m0 = blockIdx.y * 32;
    int tx = threadIdx.x, ty = threadIdx.y;
    int tid = ty * 16 + tx, lr = tid >> 5, lc = tid & 31;
    float acc[2][2] = {{0.f, 0.f}, {0.f, 0.f}};
    for (int k0 = 0; k0 < FF; k0 += 32) {
#pragma unroll
        for (int i = 0; i < 4; i++) {
            int r = lr + 8 * i;
            As[r][lc] = bf2f(QP[(size_t)(m0 + r) * FF + k0 + lc]);
            Bs[r][lc] = CTX[(size_t)(k0 + r) * CC + c0 + lc];
        }
        __syncthreads();
#pragma unroll
        for (int kk = 0; kk < 32; kk++) {
            float a0 = As[ty][kk], a1 = As[ty + 16][kk];
            float b0 = Bs[kk][tx], b1 = Bs[kk][tx + 16];
            acc[0][0] += a0 * b0; acc[0][1] += a0 * b1;
            acc[1][0] += a1 * b0; acc[1][1] += a1 * b1;
        }
        __syncthreads();
    }
#pragma unroll
    for (int i = 0; i < 2; i++)
#pragma unroll
        for (int j = 0; j < 2; j++) {
            int t = m0 + ty + 16 * i;
            size_t idx = (size_t)t * CC + c0 + tx + 16 * j;
            float addv = clampf(acc[i][j] * DINV[t], -1e6f, 1e6f);
            T[idx] = f2bf(bf2f(T[idx]) + addv);
        }
}

__global__ void colsum_k(const bf16* __restrict__ KP, float* __restrict__ KPART) {
    int chunk = blockIdx.x;
    int f = threadIdx.x;
    const bf16* base = KP + (size_t)chunk * 128 * FF + f;
    float acc = 0.f;
    for (int i = 0; i < 128; i++) acc += bf2f(base[(size_t)i * FF]);
    KPART[(size_t)chunk * FF + f] = acc;
}

__global__ void ksum_reduce(const float* __restrict__ KPART, float* __restrict__ KSUM) {
    int f = threadIdx.x;
    float acc = 0.f;
#pragma unroll
    for (int c = 0; c < 32; c++) acc += KPART[(size_t)c * FF + f];
    KSUM[f] = acc;
}

__global__ void dinv_k(const bf16* __restrict__ QP, const float* __restrict__ KSUM,
                       float* __restrict__ DINV) {
    int t = blockIdx.x * 4 + (threadIdx.x >> 6);
    int lane = threadIdx.x & 63;
    const bf16* row = QP + (size_t)t * FF;
    float s = 0.f;
#pragma unroll
    for (int j = 0; j < 4; j++) { int c = lane + 64 * j; s += bf2f(row[c]) * KSUM[c]; }
    s = wave_sum(s);
    if (lane == 0) DINV[t] = fminf(1.f / fmaxf(s, 1e-30f), 1e6f);
}

// ============================================================================
//            FAST PATH: MFMA bf16 GEMM — 128x128 tile, 4 waves
// ============================================================================
// NT semantics: C[m,n] = sum_k A[m*lda+k] * B[n*ldb+k]. All operands row-major
// with K contiguous (transposed-operand staging eliminated via TRANSC epilogue
// writes downstream). Grid: x = m-blocks (fastest -> A fetched ~once),
// y = n-blocks, z = bl*nchunk+chunk (batch + split-K).
// EPI: 0 +bias->Cb; 1 feature->Cb; 2 gelu+bias->Cb; 3 +bias+resid(Cb rmw);
//      4 fp32 partial -> Cf + z*MperZ; 5 attnout: Cb[(bl*MperZ+m)*ldc+n] += v*dinv
// TRANSC (EPI 0/1): write C^T per batch: Cb[bl*CC*NTOKB + n*NTOKB + (m&4095)],
//      bl=m>>12 — 4 consecutive-m values per lane pack into one 8B store.
template <int EPI, bool TRANSC, bool EXTB>
__global__ __launch_bounds__(256) void mfma_gemm128(
    const bf16* __restrict__ A, int lda, long long aZ,
    const void* __restrict__ Bv, int ldb, long long bZ,
    const void* __restrict__ bias, const float* __restrict__ diag,
    const float* __restrict__ dinv,
    bf16* __restrict__ Cb, int ldc, float* __restrict__ Cf,
    int MperZ, int Kc, int nchunk, const int* __restrict__ mode)
{
    __shared__ short As[128][40];   // stride 80B: 16B-aligned chunks, <=2-way banks
    __shared__ short Bs[128][40];
    int fp32 = *mode;
    int z = blockIdx.z;
    int bl = z / nchunk;
    int chunk = z - bl * nchunk;
    const short* Ag = (const short*)A + (size_t)bl * aZ;
    const short* Bg = (const short*)Bv + (size_t)bl * bZ;

    int m0 = blockIdx.x * 128, n0 = blockIdx.y * 128;
    int tid = threadIdx.x;
    int lane = tid & 63, wave = tid >> 6;
    int wm = wave >> 1, wn = wave & 1;     // wave quadrant: 64x64
    int row16 = lane & 15, quad = lane >> 4;

    f32x4 acc[4][4];
#pragma unroll
    for (int i = 0; i < 4; i++)
#pragma unroll
        for (int j = 0; j < 4; j++) acc[i][j] = {0.f, 0.f, 0.f, 0.f};

    int kBase = chunk * Kc;
    for (int kb = kBase; kb < kBase + Kc; kb += 32) {
#pragma unroll
        for (int c = tid; c < 512; c += 256) {     // 128 rows x 4 chunks of 8
            int row = c >> 2, kc = (c & 3) * 8;
            *(short8*)&As[row][kc] =
                *(const short8*)&Ag[(size_t)(m0 + row) * lda + kb + kc];
            if (EXTB && fp32) {
                const float* Bf = (const float*)Bv;
                short8 sv;
#pragma unroll
                for (int j = 0; j < 8; j++) {
                    float w = Bf[(size_t)(n0 + row) * ldb + kb + kc + j];
                    if (!(w == w)) w = 0.f;
                    sv[j] = (short)f2bits(clampf(w, -1e4f, 1e4f));
                }
                *(short8*)&Bs[row][kc] = sv;
            } else {
                *(short8*)&Bs[row][kc] =
                    *(const short8*)&Bg[(size_t)(n0 + row) * ldb + kb + kc];
            }
        }
        __syncthreads();
        short8 af[4], bfr[4];
#pragma unroll
        for (int i = 0; i < 4; i++)
            af[i] = *(const short8*)&As[wm * 64 + i * 16 + row16][quad * 8];
#pragma unroll
        for (int j = 0; j < 4; j++)
            bfr[j] = *(const short8*)&Bs[wn * 64 + j * 16 + row16][quad * 8];
#pragma unroll
        for (int i = 0; i < 4; i++)
#pragma unroll
            for (int j = 0; j < 4; j++)
                acc[i][j] = __builtin_amdgcn_mfma_f32_16x16x32_bf16(af[i], bfr[j], acc[i][j], 0, 0, 0);
        __syncthreads();
    }

#pragma unroll
    for (int i = 0; i < 4; i++)
#pragma unroll
        for (int j = 0; j < 4; j++) {
            int mb = m0 + wm * 64 + i * 16 + quad * 4;
            int n = n0 + wn * 64 + j * 16 + row16;
            if (TRANSC) {
                ushort4v pack;
#pragma unroll
                for (int r = 0; r < 4; r++) {
                    int m = mb + r;
                    float v = acc[i][j][r];
                    if (EPI == 0) {
                        v = clampf(v + ldin(bias, n, fp32), -1e6f, 1e6f);
                    } else {   // EPI == 1
                        v = fminf(0.0625f * (expf(fminf(v - diag[m], 60.f)) + 1e-4f), 1e8f);
                    }
                    pack[r] = f2bits(v);
                }
                int blq = mb >> 12, tb = mb & 4095;
                *(ushort4v*)((unsigned short*)Cb +
                    (size_t)blq * CC * NTOKB + (size_t)n * NTOKB + tb) = pack;
            } else {
#pragma unroll
                for (int r = 0; r < 4; r++) {
                    int m = mb + r;
                    float v = acc[i][j][r];
                    if (EPI == 0) {
                        v = clampf(v + ldin(bias, n, fp32), -1e6f, 1e6f);
                        Cb[(size_t)m * ldc + n] = f2bf(v);
                    } else if (EPI == 1) {
                        v = fminf(0.0625f * (expf(fminf(v - diag[m], 60.f)) + 1e-4f), 1e8f);
                        Cb[(size_t)m * ldc + n] = f2bf(v);
                    } else if (EPI == 2) {
                        v += ldin(bias, n, fp32);
                        v = 0.5f * v * (1.f + erff(v * 0.70710678118654752f));
                        Cb[(size_t)m * ldc + n] = f2bf(v);
                    } else if (EPI == 3) {
                        v += ldin(bias, n, fp32);
                        size_t idx = (size_t)m * ldc + n;
                        v = clampf(v + bf2f(Cb[idx]), -1e6f, 1e6f);
                        Cb[idx] = f2bf(v);
                    } else if (EPI == 4) {
                        Cf[(size_t)z * MperZ + (size_t)m * ldc + n] = v;
                    } else if (EPI == 5) {
                        size_t mg = (size_t)bl * MperZ + m;
                        float addv = clampf(v * dinv[mg], -1e6f, 1e6f);
                        size_t idx = mg * ldc + n;
                        Cb[idx] = f2bf(bf2f(Cb[idx]) + addv);
                    }
                }
            }
        }
}

// PART[z=bl*8+ch][f][c] (fp32) -> CTX_T[bl][c][f] (bf16)
__global__ void reduce_ctx(const float* __restrict__ PART, bf16* __restrict__ CTXT) {
    int f = blockIdx.x;       // 256
    int bl = blockIdx.y;      // GBATCH
    int c = threadIdx.x;      // 256
    float s = 0.f;
#pragma unroll
    for (int ch = 0; ch < 8; ch++)
        s += PART[(((size_t)bl * 8 + ch) * FF + f) * CC + c];
    s = clampf(s, -1e18f, 1e18f);
    CTXT[((size_t)bl * CC + c) * FF + f] = f2bf(s);
}

// row sums of KP_T[bl][f][0..4095] -> KSUM[bl][f]; one wave per (bl,f)
__global__ void colsum_t(const bf16* __restrict__ KPT, float* __restrict__ KSUM) {
    int bl = blockIdx.y;
    int f = blockIdx.x * 4 + (threadIdx.x >> 6);
    int lane = threadIdx.x & 63;
    const short* row = (const short*)KPT + ((size_t)bl * FF + f) * NTOKB;
    float s = 0.f;
    for (int i = lane * 8; i < NTOKB; i += 512) {
        short8 v = *(const short8*)&row[i];
#pragma unroll
        for (int j = 0; j < 8; j++) s += s2f(v[j]);
    }
    s = wave_sum(s);
    if (lane == 0) KSUM[(size_t)bl * FF + f] = s;
}

// D_inv per token; vectorized short4 loads
__global__ void dinv_v(const bf16* __restrict__ QP, const float* __restrict__ KSUM,
                       float* __restrict__ DINV) {
    int bl = blockIdx.y;
    int t = blockIdx.x * 4 + (threadIdx.x >> 6);
    int lane = threadIdx.x & 63;
    const short* row = (const short*)QP + ((size_t)bl * NTOKB + t) * FF;
    const float* ks = KSUM + (size_t)bl * FF;
    short4v u = *(const short4v*)&row[lane * 4];
    float s = 0.f;
#pragma unroll
    for (int j = 0; j < 4; j++) s += s2f(u[j]) * ks[lane * 4 + j];
    s = wave_sum(s);
    if (lane == 0) DINV[(size_t)bl * NTOKB + t] = fminf(1.f / fmaxf(s, 1e-30f), 1e6f);
}

// ============================================================================
extern "C" void kernel_launch(void* const* d_in, const int* in_sizes, int n_in,
                              void* d_out, int out_size, void* d_ws, size_t ws_size,
                              hipStream_t stream) {
    const void* x    = d_in[0];
    const void* proj = d_in[1];
    const void* wq   = d_in[2];
    const void* bq   = d_in[3];
    const void* wk   = d_in[4];
    const void* bk   = d_in[5];
    const void* wa   = d_in[6];
    const void* ba   = d_in[7];
    const void* g1   = d_in[8];
    const void* b1   = d_in[9];
    const void* g2   = d_in[10];
    const void* b2   = d_in[11];
    const void* w1   = d_in[12];
    const void* fb1  = d_in[13];
    const void* w2   = d_in[14];
    const void* fb2  = d_in[15];

    char* base = (char*)d_ws;
    const size_t MB = 1048576ull;
    const bool fast = ws_size >= 60 * MB;

    if (fast) {
        // ---- fast layout (peak ~57 MiB) ----
        // [0,16M)  T bf16 [32768,256]
        // [16,24M) slotH: H -> QP -> H2
        // [24,32M) slotQ: Q -> KP_T [bl][f][4096]    | MID [24M,56M) at MLP
        // [32,40M) slotK: K -> PART fp32 [32][256][256]
        // [40,48M) slotV: V_T [bl][c][4096]
        // [56M,..) smalls
        bf16* T    = (bf16*)base;
        bf16* Hs   = (bf16*)(base + 16 * MB);
        bf16* Qs   = (bf16*)(base + 24 * MB);
        bf16* Ks   = (bf16*)(base + 32 * MB);
        bf16* VT   = (bf16*)(base + 40 * MB);
        bf16* MID  = (bf16*)(base + 24 * MB);
        float* PART = (float*)(base + 32 * MB);
        char* sm = base + 56 * MB;
        int* MODE = (int*)sm;
        float* DIAGQ = (float*)(sm + 1024);
        float* DIAGK = DIAGQ + GROWS;
        float* DINV  = DIAGK + GROWS;
        float* KSUM  = DINV + GROWS;                // GBATCH*FF
        bf16* CTXT   = (bf16*)(sm + 512 * 1024);    // GBATCH*256*256 bf16 = 512K

        dim3 tb32(32, 8);
        detect_mode<<<1, 64, 0, stream>>>(x, MODE);
        transpose_in_z<<<dim3(NTOKB / 32, CC / 32, BB), tb32, 0, stream>>>(x, T, MODE);

        for (int g = 0; g < 2; g++) {
            bf16* Tg = T + (size_t)g * GROWS * CC;

            layernorm_v<<<GROWS / 4, 256, 0, stream>>>(Tg, g1, b1, Hs, MODE);
            // QKV: M=16384 N=256 K=256 — grid x=m (A fetched once)
            mfma_gemm128<0, false, true><<<dim3(128, 2, 1), 256, 0, stream>>>(
                Hs, 256, 0, wq, 256, 0, bq, nullptr, nullptr, Qs, 256,
                nullptr, 0, 256, 1, MODE);
            mfma_gemm128<0, false, true><<<dim3(128, 2, 1), 256, 0, stream>>>(
                Hs, 256, 0, wk, 256, 0, bk, nullptr, nullptr, Ks, 256,
                nullptr, 0, 256, 1, MODE);
            mfma_gemm128<0, true, true><<<dim3(128, 2, 1), 256, 0, stream>>>(
                Hs, 256, 0, wa, 256, 0, ba, nullptr, nullptr, VT, 0,
                nullptr, 0, 256, 1, MODE);
            rownorm_v<<<GROWS / 4, 256, 0, stream>>>(Qs, DIAGQ);
            rownorm_v<<<GROWS / 4, 256, 0, stream>>>(Ks, DIAGK);
            // features: QP (normal) -> slotH; KP_T (transposed) -> slotQ
            mfma_gemm128<1, false, true><<<dim3(128, 2, 1), 256, 0, stream>>>(
                Qs, 256, 0, proj, 256, 0, nullptr, DIAGQ, nullptr, Hs, 256,
                nullptr, 0, 256, 1, MODE);
            mfma_gemm128<1, true, true><<<dim3(128, 2, 1), 256, 0, stream>>>(
                Ks, 256, 0, proj, 256, 0, nullptr, DIAGK, nullptr, Qs, 0,
                nullptr, 0, 256, 1, MODE);
            bf16* QP  = Hs;
            bf16* KPT = Qs;
            colsum_t<<<dim3(FF / 4, GBATCH), 256, 0, stream>>>(KPT, KSUM);
            dinv_v<<<dim3(NTOKB / 4, GBATCH), 256, 0, stream>>>(QP, KSUM, DINV);
            // ctx: pure NT now. M=F=256, N=C=256, K=4096 split 8 ways
            mfma_gemm128<4, false, false><<<dim3(2, 2, GBATCH * 8), 256, 0, stream>>>(
                KPT, NTOKB, (long long)FF * NTOKB, VT, NTOKB, (long long)CC * NTOKB,
                nullptr, nullptr, nullptr, nullptr, CC,
                PART, FF * CC, 512, 8, MODE);
            reduce_ctx<<<dim3(FF, GBATCH), 256, 0, stream>>>(PART, CTXT);
            // attnout: M=4096/batch, N=256, K=256
            mfma_gemm128<5, false, false><<<dim3(32, 2, GBATCH), 256, 0, stream>>>(
                QP, 256, (long long)NTOKB * FF, CTXT, FF, (long long)CC * FF,
                nullptr, nullptr, DINV, Tg, 256,
                nullptr, NTOKB, 256, 1, MODE);
            // MLP
            layernorm_v<<<GROWS / 4, 256, 0, stream>>>(Tg, g2, b2, Hs, MODE);
            mfma_gemm128<2, false, true><<<dim3(128, 8, 1), 256, 0, stream>>>(
                Hs, 256, 0, w1, 256, 0, fb1, nullptr, nullptr, MID, 1024,
                nullptr, 0, 256, 1, MODE);
            mfma_gemm128<3, false, true><<<dim3(128, 2, 1), 256, 0, stream>>>(
                MID, 1024, 0, w2, 1024, 0, fb2, nullptr, nullptr, Tg, 256,
                nullptr, 0, 1024, 1, MODE);
        }
        transpose_out_z<<<dim3(CC / 32, NTOKB / 32, BB), tb32, 0, stream>>>(T, d_out, MODE);
        return;
    }

    // ================= FALLBACK: proven R5 per-batch path =================
    bf16* Tb   = (bf16*)(base);
    bf16* Hb   = (bf16*)(base + 2 * MB);
    bf16* Qb   = (bf16*)(base + 4 * MB);
    bf16* Kb   = (bf16*)(base + 6 * MB);
    bf16* Vb   = (bf16*)(base + 8 * MB);
    bf16* QPb  = (bf16*)(base + 2 * MB);
    bf16* KPb  = (bf16*)(base + 4 * MB);
    bf16* MIDb = (bf16*)(base + 2 * MB);
    bf16* H2b  = (bf16*)(base + 10 * MB);
    char* sm   = base + 12 * MB;
    int*   MODE  = (int*)sm;
    float* DIAGQ = (float*)(sm + 256);
    float* DIAGK = DIAGQ + NTOKB;
    float* DINV  = DIAGK + NTOKB;
    float* KSUM  = DINV + NTOKB;
    float* KPART = KSUM + FF;
    float* CTX   = KPART + 32 * FF;

    dim3 tb32(32, 8);
    dim3 tb16(16, 16);
    dim3 gq(CC / 32, NTOKB / 32);

    detect_mode<<<1, 64, 0, stream>>>(x, MODE);

    for (int b = 0; b < BB; b++) {
        size_t eoff = (size_t)b * CC * NTOKB;
        transpose_in_off<<<dim3(NTOKB / 32, CC / 32), tb32, 0, stream>>>(x, Tb, MODE, eoff);
        layernorm_k<<<NTOKB / 4, 256, 0, stream>>>(Tb, g1, b1, Hb, MODE);
        gemm_nt<0><<<gq, tb16, 0, stream>>>(Hb, wq, bq, nullptr, nullptr, Qb, NTOKB, CC, CC, MODE);
        gemm_nt<0><<<gq, tb16, 0, stream>>>(Hb, wk, bk, nullptr, nullptr, Kb, NTOKB, CC, CC, MODE);
        gemm_nt<0><<<gq, tb16, 0, stream>>>(Hb, wa, ba, nullptr, nullptr, Vb, NTOKB, CC, CC, MODE);
        rownorm_k<<<NTOKB / 4, 256, 0, stream>>>(Qb, DIAGQ);
        rownorm_k<<<NTOKB / 4, 256, 0, stream>>>(Kb, DIAGK);
        gemm_nt<1><<<gq, tb16, 0, stream>>>(Qb, proj, nullptr, DIAGQ, nullptr, QPb, NTOKB, FF, CC, MODE);
        gemm_nt<1><<<gq, tb16, 0, stream>>>(Kb, proj, nullptr, DIAGK, nullptr, KPb, NTOKB, FF, CC, MODE);
        colsum_k<<<32, 256, 0, stream>>>(KPb, KPART);
        ksum_reduce<<<1, 256, 0, stream>>>(KPART, KSUM);
        dinv_k<<<NTOKB / 4, 256, 0, stream>>>(QPb, KSUM, DINV);
        gemm_ctx_fb<<<dim3(CC / 32, FF / 32), tb16, 0, stream>>>(KPb, Vb, CTX);
        gemm_attnout_fb<<<gq, tb16, 0, stream>>>(QPb, CTX, DINV, Tb);
        layernorm_k<<<NTOKB / 4, 256, 0, stream>>>(Tb, g2, b2, H2b, MODE);
        gemm_nt<2><<<dim3(HIDDEN / 32, NTOKB / 32), tb16, 0, stream>>>(H2b, w1, fb1, nullptr, nullptr, MIDb, NTOKB, HIDDEN, CC, MODE);
        gemm_nt<3><<<gq, tb16, 0, stream>>>(MIDb, w2, fb2, nullptr, Tb, Tb, NTOKB, CC, HIDDEN, MODE);
        transpose_out_off<<<dim3(CC / 32, NTOKB / 32), tb32, 0, stream>>>(Tb, d_out, MODE, eoff);
    }
}

// Round 8
// 576.787 us; speedup vs baseline: 1.3077x; 1.3077x over previous
//
#include <hip/hip_runtime.h>
#include <hip/hip_bf16.h>
#include <math.h>

typedef __hip_bfloat16 bf16;
typedef __attribute__((ext_vector_type(8))) short short8;
typedef __attribute__((ext_vector_type(4))) short short4v;
typedef __attribute__((ext_vector_type(4))) unsigned short ushort4v;
typedef __attribute__((ext_vector_type(4))) float f32x4;
typedef unsigned int u32;

#define BB 8
#define CC 256
#define NTOKB 4096
#define FF 256
#define HIDDEN 1024
#define GBATCH 4
#define GROWS (GBATCH*NTOKB)   // 16384

#if defined(__has_builtin)
#if __has_builtin(__builtin_amdgcn_global_load_lds)
#define HAS_GLL 1
#endif
#endif
#ifndef HAS_GLL
#define HAS_GLL 0
#endif

__device__ __forceinline__ float bf2f(bf16 x) { return __bfloat162float(x); }
__device__ __forceinline__ bf16 f2bf(float x) { return __float2bfloat16(x); }
__device__ __forceinline__ float clampf(float v, float lo, float hi) {
    return fminf(fmaxf(v, lo), hi);
}
__device__ __forceinline__ float s2f(short s) {
    unsigned int u = ((unsigned int)(unsigned short)s) << 16;
    float f; __builtin_memcpy(&f, &u, 4); return f;
}
__device__ __forceinline__ unsigned short f2bits(float v) {
    bf16 h = f2bf(v);
    unsigned short b; __builtin_memcpy(&b, &h, 2); return b;
}

#if HAS_GLL
__device__ __forceinline__ void gll16(const void* g, void* l) {
    __builtin_amdgcn_global_load_lds(
        (const __attribute__((address_space(1))) u32*)g,
        (__attribute__((address_space(3))) u32*)l, 16, 0, 0);
}
#endif

__device__ __forceinline__ float ldin(const void* p, size_t i, int fp32mode) {
    float v = fp32mode ? ((const float*)p)[i] : __bfloat162float(((const bf16*)p)[i]);
    if (!(v == v)) v = 0.f;
    return clampf(v, -1e4f, 1e4f);
}

__device__ __forceinline__ float wave_sum(float v) {
#pragma unroll
    for (int off = 32; off > 0; off >>= 1) v += __shfl_xor(v, off, 64);
    return v;
}

__global__ void detect_mode(const void* __restrict__ x, int* __restrict__ flag) {
    int i = threadIdx.x;
    float vb = __bfloat162float(((const bf16*)x)[(size_t)i * 37 + 1]);
    int bad = (!(vb == vb)) || (fabsf(vb) > 1e4f);
    unsigned long long m = __ballot(bad);
    if (i == 0) *flag = (m != 0ull) ? 1 : 0;
}

// ============================================================================
//                     SHARED SMALL KERNELS
// ============================================================================

__global__ void transpose_in_off(const void* __restrict__ X, bf16* __restrict__ T,
                                 const int* __restrict__ mode, size_t eoff) {
    __shared__ float tile[32][33];
    int fp32 = *mode;
    int n0 = blockIdx.x * 32, c0 = blockIdx.y * 32;
    int tx = threadIdx.x, ty = threadIdx.y;
    for (int i = ty; i < 32; i += 8)
        tile[i][tx] = ldin(X, eoff + (size_t)(c0 + i) * NTOKB + n0 + tx, fp32);
    __syncthreads();
    for (int i = ty; i < 32; i += 8)
        T[(size_t)(n0 + i) * CC + c0 + tx] = f2bf(tile[tx][i]);
}

__global__ void transpose_out_off(const bf16* __restrict__ T, void* __restrict__ O,
                                  const int* __restrict__ mode, size_t eoff) {
    __shared__ float tile[32][33];
    int fp32 = *mode;
    int c0 = blockIdx.x * 32, n0 = blockIdx.y * 32;
    int tx = threadIdx.x, ty = threadIdx.y;
    for (int i = ty; i < 32; i += 8)
        tile[i][tx] = bf2f(T[(size_t)(n0 + i) * CC + c0 + tx]);
    __syncthreads();
    for (int i = ty; i < 32; i += 8) {
        size_t idx = eoff + (size_t)(c0 + i) * NTOKB + n0 + tx;
        float v = tile[tx][i];
        if (fp32) ((float*)O)[idx] = v; else ((bf16*)O)[idx] = f2bf(v);
    }
}

__global__ void transpose_in_z(const void* __restrict__ X, bf16* __restrict__ T,
                               const int* __restrict__ mode) {
    __shared__ float tile[32][33];
    int fp32 = *mode;
    int b = blockIdx.z;
    int n0 = blockIdx.x * 32, c0 = blockIdx.y * 32;
    int tx = threadIdx.x, ty = threadIdx.y;
    size_t eoff = (size_t)b * CC * NTOKB;
    for (int i = ty; i < 32; i += 8)
        tile[i][tx] = ldin(X, eoff + (size_t)(c0 + i) * NTOKB + n0 + tx, fp32);
    __syncthreads();
    for (int i = ty; i < 32; i += 8)
        T[((size_t)b * NTOKB + n0 + i) * CC + c0 + tx] = f2bf(tile[tx][i]);
}

__global__ void transpose_out_z(const bf16* __restrict__ T, void* __restrict__ O,
                                const int* __restrict__ mode) {
    __shared__ float tile[32][33];
    int fp32 = *mode;
    int b = blockIdx.z;
    int c0 = blockIdx.x * 32, n0 = blockIdx.y * 32;
    int tx = threadIdx.x, ty = threadIdx.y;
    for (int i = ty; i < 32; i += 8)
        tile[i][tx] = bf2f(T[((size_t)b * NTOKB + n0 + i) * CC + c0 + tx]);
    __syncthreads();
    for (int i = ty; i < 32; i += 8) {
        size_t idx = (size_t)b * CC * NTOKB + (size_t)(c0 + i) * NTOKB + n0 + tx;
        float v = tile[tx][i];
        if (fp32) ((float*)O)[idx] = v; else ((bf16*)O)[idx] = f2bf(v);
    }
}

__global__ void layernorm_k(const bf16* __restrict__ X, const void* __restrict__ g,
                            const void* __restrict__ bta, bf16* __restrict__ Y,
                            const int* __restrict__ mode) {
    int fp32 = *mode;
    int t = blockIdx.x * 4 + (threadIdx.x >> 6);
    int lane = threadIdx.x & 63;
    const bf16* row = X + (size_t)t * CC;
    float v[4], s = 0.f, s2 = 0.f;
#pragma unroll
    for (int j = 0; j < 4; j++) {
        v[j] = bf2f(row[lane + 64 * j]);
        s += v[j]; s2 += v[j] * v[j];
    }
    s = wave_sum(s); s2 = wave_sum(s2);
    float mu = s * (1.f / CC);
    float var = s2 * (1.f / CC) - mu * mu;
    float rstd = rsqrtf(fmaxf(var, 0.f) + 1e-5f);
    bf16* yrow = Y + (size_t)t * CC;
#pragma unroll
    for (int j = 0; j < 4; j++) {
        int c = lane + 64 * j;
        yrow[c] = f2bf((v[j] - mu) * rstd * ldin(g, c, fp32) + ldin(bta, c, fp32));
    }
}

__global__ void layernorm_v(const bf16* __restrict__ X, const void* __restrict__ g,
                            const void* __restrict__ bta, bf16* __restrict__ Y,
                            const int* __restrict__ mode) {
    int fp32 = *mode;
    int t = blockIdx.x * 4 + (threadIdx.x >> 6);
    int lane = threadIdx.x & 63;
    const short* row = (const short*)X + (size_t)t * CC;
    short4v u = *(const short4v*)&row[lane * 4];
    float v[4], s = 0.f, s2 = 0.f;
#pragma unroll
    for (int j = 0; j < 4; j++) { v[j] = s2f(u[j]); s += v[j]; s2 += v[j] * v[j]; }
    s = wave_sum(s); s2 = wave_sum(s2);
    float mu = s * (1.f / CC);
    float var = s2 * (1.f / CC) - mu * mu;
    float rstd = rsqrtf(fmaxf(var, 0.f) + 1e-5f);
    ushort4v o;
#pragma unroll
    for (int j = 0; j < 4; j++) {
        int c = lane * 4 + j;
        o[j] = f2bits((v[j] - mu) * rstd * ldin(g, c, fp32) + ldin(bta, c, fp32));
    }
    *(ushort4v*)((unsigned short*)Y + (size_t)t * CC + lane * 4) = o;
}

__global__ void rownorm_k(bf16* __restrict__ Q, float* __restrict__ DIAG) {
    int t = blockIdx.x * 4 + (threadIdx.x >> 6);
    int lane = threadIdx.x & 63;
    bf16* row = Q + (size_t)t * CC;
    float v[4], s2 = 0.f;
#pragma unroll
    for (int j = 0; j < 4; j++) { v[j] = bf2f(row[lane + 64 * j]); s2 += v[j] * v[j]; }
    s2 = wave_sum(s2);
    float nrm = sqrtf(fmaxf(s2, 0.f));
    float scale = 1.f / fmaxf(nrm, 5e-5f);
#pragma unroll
    for (int j = 0; j < 4; j++) row[lane + 64 * j] = f2bf(v[j] * scale);
    if (lane == 0) DIAG[t] = 0.5f * s2 * scale * scale;
}

__global__ void rownorm_v(bf16* __restrict__ Q, float* __restrict__ DIAG) {
    int t = blockIdx.x * 4 + (threadIdx.x >> 6);
    int lane = threadIdx.x & 63;
    short* row = (short*)Q + (size_t)t * CC;
    short4v u = *(const short4v*)&row[lane * 4];
    float v[4], s2 = 0.f;
#pragma unroll
    for (int j = 0; j < 4; j++) { v[j] = s2f(u[j]); s2 += v[j] * v[j]; }
    s2 = wave_sum(s2);
    float nrm = sqrtf(fmaxf(s2, 0.f));
    float scale = 1.f / fmaxf(nrm, 5e-5f);
    ushort4v o;
#pragma unroll
    for (int j = 0; j < 4; j++) o[j] = f2bits(v[j] * scale);
    *(ushort4v*)&row[lane * 4] = o;
    if (lane == 0) DIAG[t] = 0.5f * s2 * scale * scale;
}

// ============================================================================
//                     FALLBACK (R5) GEMM KERNELS
// ============================================================================

template <int EPI>
__global__ void gemm_nt(const bf16* __restrict__ A, const void* __restrict__ Bw,
                        const void* __restrict__ bias, const float* __restrict__ diag,
                        const bf16* __restrict__ resid, bf16* __restrict__ Cm,
                        int M, int Nn, int Kk, const int* __restrict__ mode) {
    __shared__ float As[32][33];
    __shared__ float Bs[32][33];
    int fp32 = *mode;
    int tx = threadIdx.x, ty = threadIdx.y;
    int n0 = blockIdx.x * 32, m0 = blockIdx.y * 32;
    int tid = ty * 16 + tx;
    int lr = tid >> 5, lc = tid & 31;
    float acc[2][2] = {{0.f, 0.f}, {0.f, 0.f}};
    for (int k0 = 0; k0 < Kk; k0 += 32) {
#pragma unroll
        for (int i = 0; i < 4; i++) {
            int r = lr + 8 * i;
            As[r][lc] = bf2f(A[(size_t)(m0 + r) * Kk + k0 + lc]);
            Bs[r][lc] = ldin(Bw, (size_t)(n0 + r) * Kk + k0 + lc, fp32);
        }
        __syncthreads();
#pragma unroll
        for (int kk = 0; kk < 32; kk++) {
            float a0 = As[ty][kk], a1 = As[ty + 16][kk];
            float b0 = Bs[tx][kk], b1 = Bs[tx + 16][kk];
            acc[0][0] += a0 * b0; acc[0][1] += a0 * b1;
            acc[1][0] += a1 * b0; acc[1][1] += a1 * b1;
        }
        __syncthreads();
    }
#pragma unroll
    for (int i = 0; i < 2; i++)
#pragma unroll
        for (int j = 0; j < 2; j++) {
            int m = m0 + ty + 16 * i, n = n0 + tx + 16 * j;
            float v = acc[i][j];
            if (EPI == 0) {
                v = clampf(v + ldin(bias, n, fp32), -1e6f, 1e6f);
            } else if (EPI == 1) {
                v = fminf(0.0625f * (expf(fminf(v - diag[m], 60.f)) + 1e-4f), 1e8f);
            } else if (EPI == 2) {
                v += ldin(bias, n, fp32);
                v = 0.5f * v * (1.f + erff(v * 0.70710678118654752f));
            } else if (EPI == 3) {
                v += ldin(bias, n, fp32);
                v = clampf(v + bf2f(resid[(size_t)m * Nn + n]), -1e6f, 1e6f);
            }
            Cm[(size_t)m * Nn + n] = f2bf(v);
        }
}

__global__ void gemm_ctx_fb(const bf16* __restrict__ KP, const bf16* __restrict__ V,
                            float* __restrict__ CTX) {
    __shared__ float Ks[32][33];
    __shared__ float Vs[32][33];
    int c0 = blockIdx.x * 32, f0 = blockIdx.y * 32;
    int tx = threadIdx.x, ty = threadIdx.y;
    int tid = ty * 16 + tx, lr = tid >> 5, lc = tid & 31;
    float acc[2][2] = {{0.f, 0.f}, {0.f, 0.f}};
    for (int n0 = 0; n0 < NTOKB; n0 += 32) {
#pragma unroll
        for (int i = 0; i < 4; i++) {
            int r = lr + 8 * i;
            Ks[r][lc] = bf2f(KP[(size_t)(n0 + r) * FF + f0 + lc]);
            Vs[r][lc] = bf2f(V[(size_t)(n0 + r) * CC + c0 + lc]);
        }
        __syncthreads();
#pragma unroll
        for (int kk = 0; kk < 32; kk++) {
            float a0 = Ks[kk][ty], a1 = Ks[kk][ty + 16];
            float b0 = Vs[kk][tx], b1 = Vs[kk][tx + 16];
            acc[0][0] += a0 * b0; acc[0][1] += a0 * b1;
            acc[1][0] += a1 * b0; acc[1][1] += a1 * b1;
        }
        __syncthreads();
    }
#pragma unroll
    for (int i = 0; i < 2; i++)
#pragma unroll
        for (int j = 0; j < 2; j++)
            CTX[(size_t)(f0 + ty + 16 * i) * CC + c0 + tx + 16 * j] =
                clampf(acc[i][j], -1e18f, 1e18f);
}

__global__ void gemm_attnout_fb(const bf16* __restrict__ QP, const float* __restrict__ CTX,
                                const float* __restrict__ DINV, bf16* __restrict__ T) {
    __shared__ float As[32][33];
    __shared__ float Bs[32][33];
    int c0 = blockIdx.x * 32, m0 = blockIdx.y * 32;
    int tx = threadIdx.x, ty = threadIdx.y;
    int tid = ty * 16 + tx, lr = tid >> 5, lc = tid & 31;
    float acc[2][2] = {{0.f, 0.f}, {0.f, 0.f}};
    for (int k0 = 0; k0 < FF; k0 += 32) {
#pragma unroll
        for (int i = 0; i < 4; i++) {
            int r = lr + 8 * i;
            As[r][lc] = bf2f(QP[(size_t)(m0 + r) * FF + k0 + lc]);
            Bs[r][lc] = CTX[(size_t)(k0 + r) * CC + c0 + lc];
        }
        __syncthreads();
#pragma unroll
        for (int kk = 0; kk < 32; kk++) {
            float a0 = As[ty][kk], a1 = As[ty + 16][kk];
            float b0 = Bs[kk][tx], b1 = Bs[kk][tx + 16];
            acc[0][0] += a0 * b0; acc[0][1] += a0 * b1;
            acc[1][0] += a1 * b0; acc[1][1] += a1 * b1;
        }
        __syncthreads();
    }
#pragma unroll
    for (int i = 0; i < 2; i++)
#pragma unroll
        for (int j = 0; j < 2; j++) {
            int t = m0 + ty + 16 * i;
            size_t idx = (size_t)t * CC + c0 + tx + 16 * j;
            float addv = clampf(acc[i][j] * DINV[t], -1e6f, 1e6f);
            T[idx] = f2bf(bf2f(T[idx]) + addv);
        }
}

__global__ void colsum_k(const bf16* __restrict__ KP, float* __restrict__ KPART) {
    int chunk = blockIdx.x;
    int f = threadIdx.x;
    const bf16* base = KP + (size_t)chunk * 128 * FF + f;
    float acc = 0.f;
    for (int i = 0; i < 128; i++) acc += bf2f(base[(size_t)i * FF]);
    KPART[(size_t)chunk * FF + f] = acc;
}

__global__ void ksum_reduce(const float* __restrict__ KPART, float* __restrict__ KSUM) {
    int f = threadIdx.x;
    float acc = 0.f;
#pragma unroll
    for (int c = 0; c < 32; c++) acc += KPART[(size_t)c * FF + f];
    KSUM[f] = acc;
}

__global__ void dinv_k(const bf16* __restrict__ QP, const float* __restrict__ KSUM,
                       float* __restrict__ DINV) {
    int t = blockIdx.x * 4 + (threadIdx.x >> 6);
    int lane = threadIdx.x & 63;
    const bf16* row = QP + (size_t)t * FF;
    float s = 0.f;
#pragma unroll
    for (int j = 0; j < 4; j++) { int c = lane + 64 * j; s += bf2f(row[c]) * KSUM[c]; }
    s = wave_sum(s);
    if (lane == 0) DINV[t] = fminf(1.f / fmaxf(s, 1e-30f), 1e6f);
}

// ============================================================================
//      FAST PATH: MFMA bf16 GEMM — BMx64 tile, 4 waves, global_load_lds
// ============================================================================
// NT: C[m,n] = sum_k A[m*lda+k] * B[n*ldb+k]. Grid: x=n-blocks (A-panel shared
// by consecutive blocks), y=m-blocks, z=bl*nchunk+chunk.
// Waves 2x2: wave covers (BM/2) x 32; MI=BM/32 A-frags, 2 B-frags, MI*2 MFMAs/step.
// LDS unpadded [rows][32] (required by global_load_lds); frag-read bank pattern
// meets the 8-cycle wave64 floor (no extra conflicts).
// EPI: 0 +bias; 1 feature; 2 gelu+bias; 3 +bias+resid RMW; 4 fp32 partial; 5 attnout RMW.
template <int BM, int EPI, bool TRANSC, bool EXTB>
__global__ __launch_bounds__(256) void mgemm(
    const bf16* __restrict__ A, int lda, long long aZ,
    const void* __restrict__ Bv, int ldb, long long bZ,
    const void* __restrict__ bias, const float* __restrict__ diag,
    const float* __restrict__ dinv,
    bf16* __restrict__ Cb, int ldc, float* __restrict__ Cf,
    int MperZ, int Kc, int nchunk, const int* __restrict__ mode)
{
    constexpr int MI = BM / 32;
    __shared__ short As[BM][32];
    __shared__ short Bs[64][32];
    int fp32 = *mode;
    int z = blockIdx.z;
    int bl = z / nchunk;
    int chunk = z - bl * nchunk;
    const short* Ag = (const short*)A + (size_t)bl * aZ;
    const short* Bg = (const short*)Bv + (size_t)bl * bZ;

    int n0 = blockIdx.x * 64, m0 = blockIdx.y * BM;
    int tid = threadIdx.x;
    int lane = tid & 63, wave = tid >> 6;
    int wm = wave >> 1, wn = wave & 1;
    int row16 = lane & 15, quad = lane >> 4;
    int lrow = lane >> 2, lcol = (lane & 3) * 8;

    f32x4 acc[MI][2];
#pragma unroll
    for (int i = 0; i < MI; i++)
#pragma unroll
        for (int j = 0; j < 2; j++) acc[i][j] = {0.f, 0.f, 0.f, 0.f};

    int kBase = chunk * Kc;
    for (int kb = kBase; kb < kBase + Kc; kb += 32) {
        // ---- stage A (BM x 32) ----
#pragma unroll
        for (int t = 0; t < BM / 64; t++) {
            int rbase = wave * (BM / 4) + t * 16;
            const short* gsrc = &Ag[(size_t)(m0 + rbase + lrow) * lda + kb + lcol];
#if HAS_GLL
            gll16(gsrc, &As[rbase][0]);
#else
            *(short8*)&As[rbase + lrow][lcol] = *(const short8*)gsrc;
#endif
        }
        // ---- stage B (64 x 32) ----
        if (EXTB && fp32) {
            const float* Bf = (const float*)Bv;
            int brow = tid >> 2, bcol = (tid & 3) * 8;
            short8 sv;
#pragma unroll
            for (int j = 0; j < 8; j++) {
                float w = Bf[(size_t)(n0 + brow) * ldb + kb + bcol + j];
                if (!(w == w)) w = 0.f;
                sv[j] = (short)f2bits(clampf(w, -1e4f, 1e4f));
            }
            *(short8*)&Bs[brow][bcol] = sv;
        } else {
            int rbase = wave * 16;
            const short* gsrc = &Bg[(size_t)(n0 + rbase + lrow) * ldb + kb + lcol];
#if HAS_GLL
            gll16(gsrc, &Bs[rbase][0]);
#else
            *(short8*)&Bs[rbase + lrow][lcol] = *(const short8*)gsrc;
#endif
        }
        __syncthreads();
        short8 af[MI], bfr[2];
#pragma unroll
        for (int i = 0; i < MI; i++)
            af[i] = *(const short8*)&As[wm * (BM / 2) + i * 16 + row16][quad * 8];
#pragma unroll
        for (int j = 0; j < 2; j++)
            bfr[j] = *(const short8*)&Bs[wn * 32 + j * 16 + row16][quad * 8];
#pragma unroll
        for (int i = 0; i < MI; i++)
#pragma unroll
            for (int j = 0; j < 2; j++)
                acc[i][j] = __builtin_amdgcn_mfma_f32_16x16x32_bf16(af[i], bfr[j], acc[i][j], 0, 0, 0);
        __syncthreads();
    }

#pragma unroll
    for (int i = 0; i < MI; i++)
#pragma unroll
        for (int j = 0; j < 2; j++) {
            int mb = m0 + wm * (BM / 2) + i * 16 + quad * 4;
            int n = n0 + wn * 32 + j * 16 + row16;
            if (TRANSC) {
                ushort4v pack;
#pragma unroll
                for (int r = 0; r < 4; r++) {
                    int m = mb + r;
                    float v = acc[i][j][r];
                    if (EPI == 0) {
                        v = clampf(v + ldin(bias, n, fp32), -1e6f, 1e6f);
                    } else {   // EPI == 1
                        v = fminf(0.0625f * (expf(fminf(v - diag[m], 60.f)) + 1e-4f), 1e8f);
                    }
                    pack[r] = f2bits(v);
                }
                int blq = mb >> 12, tb = mb & 4095;
                *(ushort4v*)((unsigned short*)Cb +
                    (size_t)blq * CC * NTOKB + (size_t)n * NTOKB + tb) = pack;
            } else {
#pragma unroll
                for (int r = 0; r < 4; r++) {
                    int m = mb + r;
                    float v = acc[i][j][r];
                    if (EPI == 0) {
                        v = clampf(v + ldin(bias, n, fp32), -1e6f, 1e6f);
                        Cb[(size_t)m * ldc + n] = f2bf(v);
                    } else if (EPI == 1) {
                        v = fminf(0.0625f * (expf(fminf(v - diag[m], 60.f)) + 1e-4f), 1e8f);
                        Cb[(size_t)m * ldc + n] = f2bf(v);
                    } else if (EPI == 2) {
                        v += ldin(bias, n, fp32);
                        v = 0.5f * v * (1.f + erff(v * 0.70710678118654752f));
                        Cb[(size_t)m * ldc + n] = f2bf(v);
                    } else if (EPI == 3) {
                        v += ldin(bias, n, fp32);
                        size_t idx = (size_t)m * ldc + n;
                        v = clampf(v + bf2f(Cb[idx]), -1e6f, 1e6f);
                        Cb[idx] = f2bf(v);
                    } else if (EPI == 4) {
                        Cf[(size_t)z * MperZ + (size_t)m * ldc + n] = v;
                    } else if (EPI == 5) {
                        size_t mg = (size_t)bl * MperZ + m;
                        float addv = clampf(v * dinv[mg], -1e6f, 1e6f);
                        size_t idx = mg * ldc + n;
                        Cb[idx] = f2bf(bf2f(Cb[idx]) + addv);
                    }
                }
            }
        }
}

// PART[z=bl*8+ch][f][c] (fp32) -> CTX_T[bl][c][f] (bf16)
__global__ void reduce_ctx(const float* __restrict__ PART, bf16* __restrict__ CTXT) {
    int f = blockIdx.x;
    int bl = blockIdx.y;
    int c = threadIdx.x;
    float s = 0.f;
#pragma unroll
    for (int ch = 0; ch < 8; ch++)
        s += PART[(((size_t)bl * 8 + ch) * FF + f) * CC + c];
    s = clampf(s, -1e18f, 1e18f);
    CTXT[((size_t)bl * CC + c) * FF + f] = f2bf(s);
}

__global__ void colsum_t(const bf16* __restrict__ KPT, float* __restrict__ KSUM) {
    int bl = blockIdx.y;
    int f = blockIdx.x * 4 + (threadIdx.x >> 6);
    int lane = threadIdx.x & 63;
    const short* row = (const short*)KPT + ((size_t)bl * FF + f) * NTOKB;
    float s = 0.f;
    for (int i = lane * 8; i < NTOKB; i += 512) {
        short8 v = *(const short8*)&row[i];
#pragma unroll
        for (int j = 0; j < 8; j++) s += s2f(v[j]);
    }
    s = wave_sum(s);
    if (lane == 0) KSUM[(size_t)bl * FF + f] = s;
}

__global__ void dinv_v(const bf16* __restrict__ QP, const float* __restrict__ KSUM,
                       float* __restrict__ DINV) {
    int bl = blockIdx.y;
    int t = blockIdx.x * 4 + (threadIdx.x >> 6);
    int lane = threadIdx.x & 63;
    const short* row = (const short*)QP + ((size_t)bl * NTOKB + t) * FF;
    const float* ks = KSUM + (size_t)bl * FF;
    short4v u = *(const short4v*)&row[lane * 4];
    float s = 0.f;
#pragma unroll
    for (int j = 0; j < 4; j++) s += s2f(u[j]) * ks[lane * 4 + j];
    s = wave_sum(s);
    if (lane == 0) DINV[(size_t)bl * NTOKB + t] = fminf(1.f / fmaxf(s, 1e-30f), 1e6f);
}

// ============================================================================
extern "C" void kernel_launch(void* const* d_in, const int* in_sizes, int n_in,
                              void* d_out, int out_size, void* d_ws, size_t ws_size,
                              hipStream_t stream) {
    const void* x    = d_in[0];
    const void* proj = d_in[1];
    const void* wq   = d_in[2];
    const void* bq   = d_in[3];
    const void* wk   = d_in[4];
    const void* bk   = d_in[5];
    const void* wa   = d_in[6];
    const void* ba   = d_in[7];
    const void* g1   = d_in[8];
    const void* b1   = d_in[9];
    const void* g2   = d_in[10];
    const void* b2   = d_in[11];
    const void* w1   = d_in[12];
    const void* fb1  = d_in[13];
    const void* w2   = d_in[14];
    const void* fb2  = d_in[15];

    char* base = (char*)d_ws;
    const size_t MB = 1048576ull;
    const bool fast = ws_size >= 60 * MB;

    if (fast) {
        bf16* T    = (bf16*)base;                   // [0,16M)
        bf16* Hs   = (bf16*)(base + 16 * MB);       // H -> QP -> H2
        bf16* Qs   = (bf16*)(base + 24 * MB);       // Q -> KP_T
        bf16* Ks   = (bf16*)(base + 32 * MB);       // K -> PART
        bf16* VT   = (bf16*)(base + 40 * MB);       // V_T
        bf16* MID  = (bf16*)(base + 24 * MB);       // MLP hidden [16384,1024]
        float* PART = (float*)(base + 32 * MB);
        char* sm = base + 56 * MB;
        int* MODE = (int*)sm;
        float* DIAGQ = (float*)(sm + 1024);
        float* DIAGK = DIAGQ + GROWS;
        float* DINV  = DIAGK + GROWS;
        float* KSUM  = DINV + GROWS;
        bf16* CTXT   = (bf16*)(sm + 512 * 1024);

        dim3 tb32(32, 8);
        detect_mode<<<1, 64, 0, stream>>>(x, MODE);
        transpose_in_z<<<dim3(NTOKB / 32, CC / 32, BB), tb32, 0, stream>>>(x, T, MODE);

        for (int g = 0; g < 2; g++) {
            bf16* Tg = T + (size_t)g * GROWS * CC;

            layernorm_v<<<GROWS / 4, 256, 0, stream>>>(Tg, g1, b1, Hs, MODE);
            // QKV: M=16384 N=256 K=256; grid (n=4, m=128) = 512 blocks
            mgemm<128, 0, false, true><<<dim3(4, 128, 1), 256, 0, stream>>>(
                Hs, 256, 0, wq, 256, 0, bq, nullptr, nullptr, Qs, 256,
                nullptr, 0, 256, 1, MODE);
            mgemm<128, 0, false, true><<<dim3(4, 128, 1), 256, 0, stream>>>(
                Hs, 256, 0, wk, 256, 0, bk, nullptr, nullptr, Ks, 256,
                nullptr, 0, 256, 1, MODE);
            mgemm<128, 0, true, true><<<dim3(4, 128, 1), 256, 0, stream>>>(
                Hs, 256, 0, wa, 256, 0, ba, nullptr, nullptr, VT, 0,
                nullptr, 0, 256, 1, MODE);
            rownorm_v<<<GROWS / 4, 256, 0, stream>>>(Qs, DIAGQ);
            rownorm_v<<<GROWS / 4, 256, 0, stream>>>(Ks, DIAGK);
            mgemm<128, 1, false, true><<<dim3(4, 128, 1), 256, 0, stream>>>(
                Qs, 256, 0, proj, 256, 0, nullptr, DIAGQ, nullptr, Hs, 256,
                nullptr, 0, 256, 1, MODE);
            mgemm<128, 1, true, true><<<dim3(4, 128, 1), 256, 0, stream>>>(
                Ks, 256, 0, proj, 256, 0, nullptr, DIAGK, nullptr, Qs, 0,
                nullptr, 0, 256, 1, MODE);
            bf16* QP  = Hs;
            bf16* KPT = Qs;
            colsum_t<<<dim3(FF / 4, GBATCH), 256, 0, stream>>>(KPT, KSUM);
            dinv_v<<<dim3(NTOKB / 4, GBATCH), 256, 0, stream>>>(QP, KSUM, DINV);
            // ctx: M=F=256, N=C=256, K=4096 split 8; 64x64 tile -> 512 blocks
            mgemm<64, 4, false, false><<<dim3(4, 4, GBATCH * 8), 256, 0, stream>>>(
                KPT, NTOKB, (long long)FF * NTOKB, VT, NTOKB, (long long)CC * NTOKB,
                nullptr, nullptr, nullptr, nullptr, CC,
                PART, FF * CC, 512, 8, MODE);
            reduce_ctx<<<dim3(FF, GBATCH), 256, 0, stream>>>(PART, CTXT);
            // attnout: M=4096/batch, N=256, K=256; (4, 32, 4) = 512 blocks
            mgemm<128, 5, false, false><<<dim3(4, 32, GBATCH), 256, 0, stream>>>(
                QP, 256, (long long)NTOKB * FF, CTXT, FF, (long long)CC * FF,
                nullptr, nullptr, DINV, Tg, 256,
                nullptr, NTOKB, 256, 1, MODE);
            // MLP
            layernorm_v<<<GROWS / 4, 256, 0, stream>>>(Tg, g2, b2, Hs, MODE);
            mgemm<128, 2, false, true><<<dim3(16, 128, 1), 256, 0, stream>>>(
                Hs, 256, 0, w1, 256, 0, fb1, nullptr, nullptr, MID, 1024,
                nullptr, 0, 256, 1, MODE);
            mgemm<128, 3, false, true><<<dim3(4, 128, 1), 256, 0, stream>>>(
                MID, 1024, 0, w2, 1024, 0, fb2, nullptr, nullptr, Tg, 256,
                nullptr, 0, 1024, 1, MODE);
        }
        transpose_out_z<<<dim3(CC / 32, NTOKB / 32, BB), tb32, 0, stream>>>(T, d_out, MODE);
        return;
    }

    // ================= FALLBACK: proven R5 per-batch path =================
    bf16* Tb   = (bf16*)(base);
    bf16* Hb   = (bf16*)(base + 2 * MB);
    bf16* Qb   = (bf16*)(base + 4 * MB);
    bf16* Kb   = (bf16*)(base + 6 * MB);
    bf16* Vb   = (bf16*)(base + 8 * MB);
    bf16* QPb  = (bf16*)(base + 2 * MB);
    bf16* KPb  = (bf16*)(base + 4 * MB);
    bf16* MIDb = (bf16*)(base + 2 * MB);
    bf16* H2b  = (bf16*)(base + 10 * MB);
    char* sm   = base + 12 * MB;
    int*   MODE  = (int*)sm;
    float* DIAGQ = (float*)(sm + 256);
    float* DIAGK = DIAGQ + NTOKB;
    float* DINV  = DIAGK + NTOKB;
    float* KSUM  = DINV + NTOKB;
    float* KPART = KSUM + FF;
    float* CTX   = KPART + 32 * FF;

    dim3 tb32(32, 8);
    dim3 tb16(16, 16);
    dim3 gq(CC / 32, NTOKB / 32);

    detect_mode<<<1, 64, 0, stream>>>(x, MODE);

    for (int b = 0; b < BB; b++) {
        size_t eoff = (size_t)b * CC * NTOKB;
        transpose_in_off<<<dim3(NTOKB / 32, CC / 32), tb32, 0, stream>>>(x, Tb, MODE, eoff);
        layernorm_k<<<NTOKB / 4, 256, 0, stream>>>(Tb, g1, b1, Hb, MODE);
        gemm_nt<0><<<gq, tb16, 0, stream>>>(Hb, wq, bq, nullptr, nullptr, Qb, NTOKB, CC, CC, MODE);
        gemm_nt<0><<<gq, tb16, 0, stream>>>(Hb, wk, bk, nullptr, nullptr, Kb, NTOKB, CC, CC, MODE);
        gemm_nt<0><<<gq, tb16, 0, stream>>>(Hb, wa, ba, nullptr, nullptr, Vb, NTOKB, CC, CC, MODE);
        rownorm_k<<<NTOKB / 4, 256, 0, stream>>>(Qb, DIAGQ);
        rownorm_k<<<NTOKB / 4, 256, 0, stream>>>(Kb, DIAGK);
        gemm_nt<1><<<gq, tb16, 0, stream>>>(Qb, proj, nullptr, DIAGQ, nullptr, QPb, NTOKB, FF, CC, MODE);
        gemm_nt<1><<<gq, tb16, 0, stream>>>(Kb, proj, nullptr, DIAGK, nullptr, KPb, NTOKB, FF, CC, MODE);
        colsum_k<<<32, 256, 0, stream>>>(KPb, KPART);
        ksum_reduce<<<1, 256, 0, stream>>>(KPART, KSUM);
        dinv_k<<<NTOKB / 4, 256, 0, stream>>>(QPb, KSUM, DINV);
        gemm_ctx_fb<<<dim3(CC / 32, FF / 32), tb16, 0, stream>>>(KPb, Vb, CTX);
        gemm_attnout_fb<<<gq, tb16, 0, stream>>>(QPb, CTX, DINV, Tb);
        layernorm_k<<<NTOKB / 4, 256, 0, stream>>>(Tb, g2, b2, H2b, MODE);
        gemm_nt<2><<<dim3(HIDDEN / 32, NTOKB / 32), tb16, 0, stream>>>(H2b, w1, fb1, nullptr, nullptr, MIDb, NTOKB, HIDDEN, CC, MODE);
        gemm_nt<3><<<gq, tb16, 0, stream>>>(MIDb, w2, fb2, nullptr, Tb, Tb, NTOKB, CC, HIDDEN, MODE);
        transpose_out_off<<<dim3(CC / 32, NTOKB / 32), tb32, 0, stream>>>(Tb, d_out, MODE, eoff);
    }
}

// Round 9
// 442.449 us; speedup vs baseline: 1.7048x; 1.3036x over previous
//
#include <hip/hip_runtime.h>
#include <hip/hip_bf16.h>
#include <math.h>

typedef __hip_bfloat16 bf16;
typedef __attribute__((ext_vector_type(8))) short short8;
typedef __attribute__((ext_vector_type(4))) short short4v;
typedef __attribute__((ext_vector_type(4))) unsigned short ushort4v;
typedef __attribute__((ext_vector_type(4))) float f32x4;
typedef unsigned int u32;

#define BB 8
#define CC 256
#define NTOKB 4096
#define FF 256
#define HIDDEN 1024
#define NTOK (BB*NTOKB)     // 32768

#if defined(__has_builtin)
#if __has_builtin(__builtin_amdgcn_global_load_lds)
#define HAS_GLL 1
#endif
#endif
#ifndef HAS_GLL
#define HAS_GLL 0
#endif

__device__ __forceinline__ float bf2f(bf16 x) { return __bfloat162float(x); }
__device__ __forceinline__ bf16 f2bf(float x) { return __float2bfloat16(x); }
__device__ __forceinline__ float clampf(float v, float lo, float hi) {
    return fminf(fmaxf(v, lo), hi);
}
__device__ __forceinline__ float s2f(short s) {
    unsigned int u = ((unsigned int)(unsigned short)s) << 16;
    float f; __builtin_memcpy(&f, &u, 4); return f;
}
__device__ __forceinline__ unsigned short f2bits(float v) {
    bf16 h = f2bf(v);
    unsigned short b; __builtin_memcpy(&b, &h, 2); return b;
}

#if HAS_GLL
__device__ __forceinline__ void gll16(const void* g, void* l) {
    __builtin_amdgcn_global_load_lds(
        (const __attribute__((address_space(1))) u32*)g,
        (__attribute__((address_space(3))) u32*)l, 16, 0, 0);
}
#endif

__device__ __forceinline__ float ldin(const void* p, size_t i, int fp32mode) {
    float v = fp32mode ? ((const float*)p)[i] : __bfloat162float(((const bf16*)p)[i]);
    if (!(v == v)) v = 0.f;
    return clampf(v, -1e4f, 1e4f);
}

__device__ __forceinline__ float wave_sum(float v) {
#pragma unroll
    for (int off = 32; off > 0; off >>= 1) v += __shfl_xor(v, off, 64);
    return v;
}

__global__ void detect_mode(const void* __restrict__ x, int* __restrict__ flag) {
    int i = threadIdx.x;
    float vb = __bfloat162float(((const bf16*)x)[(size_t)i * 37 + 1]);
    int bad = (!(vb == vb)) || (fabsf(vb) > 1e4f);
    unsigned long long m = __ballot(bad);
    if (i == 0) *flag = (m != 0ull) ? 1 : 0;
}

// ============================================================================
//                     SHARED SMALL KERNELS
// ============================================================================

__global__ void transpose_in_off(const void* __restrict__ X, bf16* __restrict__ T,
                                 const int* __restrict__ mode, size_t eoff) {
    __shared__ float tile[32][33];
    int fp32 = *mode;
    int n0 = blockIdx.x * 32, c0 = blockIdx.y * 32;
    int tx = threadIdx.x, ty = threadIdx.y;
    for (int i = ty; i < 32; i += 8)
        tile[i][tx] = ldin(X, eoff + (size_t)(c0 + i) * NTOKB + n0 + tx, fp32);
    __syncthreads();
    for (int i = ty; i < 32; i += 8)
        T[(size_t)(n0 + i) * CC + c0 + tx] = f2bf(tile[tx][i]);
}

__global__ void transpose_out_off(const bf16* __restrict__ T, void* __restrict__ O,
                                  const int* __restrict__ mode, size_t eoff) {
    __shared__ float tile[32][33];
    int fp32 = *mode;
    int c0 = blockIdx.x * 32, n0 = blockIdx.y * 32;
    int tx = threadIdx.x, ty = threadIdx.y;
    for (int i = ty; i < 32; i += 8)
        tile[i][tx] = bf2f(T[(size_t)(n0 + i) * CC + c0 + tx]);
    __syncthreads();
    for (int i = ty; i < 32; i += 8) {
        size_t idx = eoff + (size_t)(c0 + i) * NTOKB + n0 + tx;
        float v = tile[tx][i];
        if (fp32) ((float*)O)[idx] = v; else ((bf16*)O)[idx] = f2bf(v);
    }
}

__global__ void transpose_in_z(const void* __restrict__ X, bf16* __restrict__ T,
                               const int* __restrict__ mode) {
    __shared__ float tile[32][33];
    int fp32 = *mode;
    int b = blockIdx.z;
    int n0 = blockIdx.x * 32, c0 = blockIdx.y * 32;
    int tx = threadIdx.x, ty = threadIdx.y;
    size_t eoff = (size_t)b * CC * NTOKB;
    for (int i = ty; i < 32; i += 8)
        tile[i][tx] = ldin(X, eoff + (size_t)(c0 + i) * NTOKB + n0 + tx, fp32);
    __syncthreads();
    for (int i = ty; i < 32; i += 8)
        T[((size_t)b * NTOKB + n0 + i) * CC + c0 + tx] = f2bf(tile[tx][i]);
}

__global__ void transpose_out_z(const bf16* __restrict__ T, void* __restrict__ O,
                                const int* __restrict__ mode) {
    __shared__ float tile[32][33];
    int fp32 = *mode;
    int b = blockIdx.z;
    int c0 = blockIdx.x * 32, n0 = blockIdx.y * 32;
    int tx = threadIdx.x, ty = threadIdx.y;
    for (int i = ty; i < 32; i += 8)
        tile[i][tx] = bf2f(T[((size_t)b * NTOKB + n0 + i) * CC + c0 + tx]);
    __syncthreads();
    for (int i = ty; i < 32; i += 8) {
        size_t idx = (size_t)b * CC * NTOKB + (size_t)(c0 + i) * NTOKB + n0 + tx;
        float v = tile[tx][i];
        if (fp32) ((float*)O)[idx] = v; else ((bf16*)O)[idx] = f2bf(v);
    }
}

__global__ void layernorm_k(const bf16* __restrict__ X, const void* __restrict__ g,
                            const void* __restrict__ bta, bf16* __restrict__ Y,
                            const int* __restrict__ mode) {
    int fp32 = *mode;
    int t = blockIdx.x * 4 + (threadIdx.x >> 6);
    int lane = threadIdx.x & 63;
    const bf16* row = X + (size_t)t * CC;
    float v[4], s = 0.f, s2 = 0.f;
#pragma unroll
    for (int j = 0; j < 4; j++) {
        v[j] = bf2f(row[lane + 64 * j]);
        s += v[j]; s2 += v[j] * v[j];
    }
    s = wave_sum(s); s2 = wave_sum(s2);
    float mu = s * (1.f / CC);
    float var = s2 * (1.f / CC) - mu * mu;
    float rstd = rsqrtf(fmaxf(var, 0.f) + 1e-5f);
    bf16* yrow = Y + (size_t)t * CC;
#pragma unroll
    for (int j = 0; j < 4; j++) {
        int c = lane + 64 * j;
        yrow[c] = f2bf((v[j] - mu) * rstd * ldin(g, c, fp32) + ldin(bta, c, fp32));
    }
}

__global__ void layernorm_v(const bf16* __restrict__ X, const void* __restrict__ g,
                            const void* __restrict__ bta, bf16* __restrict__ Y,
                            const int* __restrict__ mode) {
    int fp32 = *mode;
    int t = blockIdx.x * 4 + (threadIdx.x >> 6);
    int lane = threadIdx.x & 63;
    const short* row = (const short*)X + (size_t)t * CC;
    short4v u = *(const short4v*)&row[lane * 4];
    float v[4], s = 0.f, s2 = 0.f;
#pragma unroll
    for (int j = 0; j < 4; j++) { v[j] = s2f(u[j]); s += v[j]; s2 += v[j] * v[j]; }
    s = wave_sum(s); s2 = wave_sum(s2);
    float mu = s * (1.f / CC);
    float var = s2 * (1.f / CC) - mu * mu;
    float rstd = rsqrtf(fmaxf(var, 0.f) + 1e-5f);
    ushort4v o;
#pragma unroll
    for (int j = 0; j < 4; j++) {
        int c = lane * 4 + j;
        o[j] = f2bits((v[j] - mu) * rstd * ldin(g, c, fp32) + ldin(bta, c, fp32));
    }
    *(ushort4v*)((unsigned short*)Y + (size_t)t * CC + lane * 4) = o;
}

__global__ void rownorm_k(bf16* __restrict__ Q, float* __restrict__ DIAG) {
    int t = blockIdx.x * 4 + (threadIdx.x >> 6);
    int lane = threadIdx.x & 63;
    bf16* row = Q + (size_t)t * CC;
    float v[4], s2 = 0.f;
#pragma unroll
    for (int j = 0; j < 4; j++) { v[j] = bf2f(row[lane + 64 * j]); s2 += v[j] * v[j]; }
    s2 = wave_sum(s2);
    float nrm = sqrtf(fmaxf(s2, 0.f));
    float scale = 1.f / fmaxf(nrm, 5e-5f);
#pragma unroll
    for (int j = 0; j < 4; j++) row[lane + 64 * j] = f2bf(v[j] * scale);
    if (lane == 0) DIAG[t] = 0.5f * s2 * scale * scale;
}

__global__ void rownorm_v(bf16* __restrict__ Q, float* __restrict__ DIAG) {
    int t = blockIdx.x * 4 + (threadIdx.x >> 6);
    int lane = threadIdx.x & 63;
    short* row = (short*)Q + (size_t)t * CC;
    short4v u = *(const short4v*)&row[lane * 4];
    float v[4], s2 = 0.f;
#pragma unroll
    for (int j = 0; j < 4; j++) { v[j] = s2f(u[j]); s2 += v[j] * v[j]; }
    s2 = wave_sum(s2);
    float nrm = sqrtf(fmaxf(s2, 0.f));
    float scale = 1.f / fmaxf(nrm, 5e-5f);
    ushort4v o;
#pragma unroll
    for (int j = 0; j < 4; j++) o[j] = f2bits(v[j] * scale);
    *(ushort4v*)&row[lane * 4] = o;
    if (lane == 0) DIAG[t] = 0.5f * s2 * scale * scale;
}

// ============================================================================
//                     FALLBACK (R5) GEMM KERNELS
// ============================================================================

template <int EPI>
__global__ void gemm_nt(const bf16* __restrict__ A, const void* __restrict__ Bw,
                        const void* __restrict__ bias, const float* __restrict__ diag,
                        const bf16* __restrict__ resid, bf16* __restrict__ Cm,
                        int M, int Nn, int Kk, const int* __restrict__ mode) {
    __shared__ float As[32][33];
    __shared__ float Bs[32][33];
    int fp32 = *mode;
    int tx = threadIdx.x, ty = threadIdx.y;
    int n0 = blockIdx.x * 32, m0 = blockIdx.y * 32;
    int tid = ty * 16 + tx;
    int lr = tid >> 5, lc = tid & 31;
    float acc[2][2] = {{0.f, 0.f}, {0.f, 0.f}};
    for (int k0 = 0; k0 < Kk; k0 += 32) {
#pragma unroll
        for (int i = 0; i < 4; i++) {
            int r = lr + 8 * i;
            As[r][lc] = bf2f(A[(size_t)(m0 + r) * Kk + k0 + lc]);
            Bs[r][lc] = ldin(Bw, (size_t)(n0 + r) * Kk + k0 + lc, fp32);
        }
        __syncthreads();
#pragma unroll
        for (int kk = 0; kk < 32; kk++) {
            float a0 = As[ty][kk], a1 = As[ty + 16][kk];
            float b0 = Bs[tx][kk], b1 = Bs[tx + 16][kk];
            acc[0][0] += a0 * b0; acc[0][1] += a0 * b1;
            acc[1][0] += a1 * b0; acc[1][1] += a1 * b1;
        }
        __syncthreads();
    }
#pragma unroll
    for (int i = 0; i < 2; i++)
#pragma unroll
        for (int j = 0; j < 2; j++) {
            int m = m0 + ty + 16 * i, n = n0 + tx + 16 * j;
            float v = acc[i][j];
            if (EPI == 0) {
                v = clampf(v + ldin(bias, n, fp32), -1e6f, 1e6f);
            } else if (EPI == 1) {
                v = fminf(0.0625f * (expf(fminf(v - diag[m], 60.f)) + 1e-4f), 1e8f);
            } else if (EPI == 2) {
                v += ldin(bias, n, fp32);
                v = 0.5f * v * (1.f + erff(v * 0.70710678118654752f));
            } else if (EPI == 3) {
                v += ldin(bias, n, fp32);
                v = clampf(v + bf2f(resid[(size_t)m * Nn + n]), -1e6f, 1e6f);
            }
            Cm[(size_t)m * Nn + n] = f2bf(v);
        }
}

__global__ void gemm_ctx_fb(const bf16* __restrict__ KP, const bf16* __restrict__ V,
                            float* __restrict__ CTX) {
    __shared__ float Ks[32][33];
    __shared__ float Vs[32][33];
    int c0 = blockIdx.x * 32, f0 = blockIdx.y * 32;
    int tx = threadIdx.x, ty = threadIdx.y;
    int tid = ty * 16 + tx, lr = tid >> 5, lc = tid & 31;
    float acc[2][2] = {{0.f, 0.f}, {0.f, 0.f}};
    for (int n0 = 0; n0 < NTOKB; n0 += 32) {
#pragma unroll
        for (int i = 0; i < 4; i++) {
            int r = lr + 8 * i;
            Ks[r][lc] = bf2f(KP[(size_t)(n0 + r) * FF + f0 + lc]);
            Vs[r][lc] = bf2f(V[(size_t)(n0 + r) * CC + c0 + lc]);
        }
        __syncthreads();
#pragma unroll
        for (int kk = 0; kk < 32; kk++) {
            float a0 = Ks[kk][ty], a1 = Ks[kk][ty + 16];
            float b0 = Vs[kk][tx], b1 = Vs[kk][tx + 16];
            acc[0][0] += a0 * b0; acc[0][1] += a0 * b1;
            acc[1][0] += a1 * b0; acc[1][1] += a1 * b1;
        }
        __syncthreads();
    }
#pragma unroll
    for (int i = 0; i < 2; i++)
#pragma unroll
        for (int j = 0; j < 2; j++)
            CTX[(size_t)(f0 + ty + 16 * i) * CC + c0 + tx + 16 * j] =
                clampf(acc[i][j], -1e18f, 1e18f);
}

__global__ void gemm_attnout_fb(const bf16* __restrict__ QP, const float* __restrict__ CTX,
                                const float* __restrict__ DINV, bf16* __restrict__ T) {
    __shared__ float As[32][33];
    __shared__ float Bs[32][33];
    int c0 = blockIdx.x * 32, m0 = blockIdx.y * 32;
    int tx = threadIdx.x, ty = threadIdx.y;
    int tid = ty * 16 + tx, lr = tid >> 5, lc = tid & 31;
    float acc[2][2] = {{0.f, 0.f}, {0.f, 0.f}};
    for (int k0 = 0; k0 < FF; k0 += 32) {
#pragma unroll
        for (int i = 0; i < 4; i++) {
            int r = lr + 8 * i;
            As[r][lc] = bf2f(QP[(size_t)(m0 + r) * FF + k0 + lc]);
            Bs[r][lc] = CTX[(size_t)(k0 + r) * CC + c0 + lc];
        }
        __syncthreads();
#pragma unroll
        for (int kk = 0; kk < 32; kk++) {
            float a0 = As[ty][kk], a1 = As[ty + 16][kk];
            float b0 = Bs[kk][tx], b1 = Bs[kk][tx + 16];
            acc[0][0] += a0 * b0; acc[0][1] += a0 * b1;
            acc[1][0] += a1 * b0; acc[1][1] += a1 * b1;
        }
        __syncthreads();
    }
#pragma unroll
    for (int i = 0; i < 2; i++)
#pragma unroll
        for (int j = 0; j < 2; j++) {
            int t = m0 + ty + 16 * i;
            size_t idx = (size_t)t * CC + c0 + tx + 16 * j;
            float addv = clampf(acc[i][j] * DINV[t], -1e6f, 1e6f);
            T[idx] = f2bf(bf2f(T[idx]) + addv);
        }
}

__global__ void colsum_k(const bf16* __restrict__ KP, float* __restrict__ KPART) {
    int chunk = blockIdx.x;
    int f = threadIdx.x;
    const bf16* base = KP + (size_t)chunk * 128 * FF + f;
    float acc = 0.f;
    for (int i = 0; i < 128; i++) acc += bf2f(base[(size_t)i * FF]);
    KPART[(size_t)chunk * FF + f] = acc;
}

__global__ void ksum_reduce(const float* __restrict__ KPART, float* __restrict__ KSUM) {
    int f = threadIdx.x;
    float acc = 0.f;
#pragma unroll
    for (int c = 0; c < 32; c++) acc += KPART[(size_t)c * FF + f];
    KSUM[f] = acc;
}

__global__ void dinv_k(const bf16* __restrict__ QP, const float* __restrict__ KSUM,
                       float* __restrict__ DINV) {
    int t = blockIdx.x * 4 + (threadIdx.x >> 6);
    int lane = threadIdx.x & 63;
    const bf16* row = QP + (size_t)t * FF;
    float s = 0.f;
#pragma unroll
    for (int j = 0; j < 4; j++) { int c = lane + 64 * j; s += bf2f(row[c]) * KSUM[c]; }
    s = wave_sum(s);
    if (lane == 0) DINV[t] = fminf(1.f / fmaxf(s, 1e-30f), 1e6f);
}

// ============================================================================
//   FAST PATH: MFMA bf16 GEMM — BMx64 tile, 4 waves, global_load_lds,
//   XCD-aware swizzle (same-m n-blocks share an XCD's L2 for the A panel)
// ============================================================================
template <int BM, int EPI, bool TRANSC, bool EXTB>
__global__ __launch_bounds__(256) void mgemm(
    const bf16* __restrict__ A, int lda, long long aZ,
    const void* __restrict__ Bv, int ldb, long long bZ,
    const void* __restrict__ bias, const float* __restrict__ diag,
    const float* __restrict__ dinv,
    bf16* __restrict__ Cb, int ldc, float* __restrict__ Cf,
    int MperZ, int Kc, int nchunk, const int* __restrict__ mode)
{
    constexpr int MI = BM / 32;
    __shared__ short As[BM][32];
    __shared__ short Bs[64][32];
    int fp32 = *mode;
    int z = blockIdx.z;
    int bl = z / nchunk;
    int chunk = z - bl * nchunk;
    const short* Ag = (const short*)A + (size_t)bl * aZ;
    const short* Bg = (const short*)Bv + (size_t)bl * bZ;

    // XCD swizzle: give the NB n-blocks of one m-panel linear ids differing by
    // 8 so round-robin dispatch puts them on the SAME XCD (A-panel L2 reuse).
    int bx = blockIdx.x, by = blockIdx.y;
    if ((gridDim.y & 7) == 0) {
        int NB = gridDim.x;
        int flat = by * NB + bx;
        int grp = flat / (8 * NB);
        int rem = flat - grp * 8 * NB;
        by = grp * 8 + (rem & 7);
        bx = rem >> 3;
    }
    int n0 = bx * 64, m0 = by * BM;

    int tid = threadIdx.x;
    int lane = tid & 63, wave = tid >> 6;
    int wm = wave >> 1, wn = wave & 1;
    int row16 = lane & 15, quad = lane >> 4;
    int lrow = lane >> 2, lcol = (lane & 3) * 8;

    f32x4 acc[MI][2];
#pragma unroll
    for (int i = 0; i < MI; i++)
#pragma unroll
        for (int j = 0; j < 2; j++) acc[i][j] = {0.f, 0.f, 0.f, 0.f};

    int kBase = chunk * Kc;
    for (int kb = kBase; kb < kBase + Kc; kb += 32) {
#pragma unroll
        for (int t = 0; t < BM / 64; t++) {
            int rbase = wave * (BM / 4) + t * 16;
            const short* gsrc = &Ag[(size_t)(m0 + rbase + lrow) * lda + kb + lcol];
#if HAS_GLL
            gll16(gsrc, &As[rbase][0]);
#else
            *(short8*)&As[rbase + lrow][lcol] = *(const short8*)gsrc;
#endif
        }
        if (EXTB && fp32) {
            const float* Bf = (const float*)Bv;
            int brow = tid >> 2, bcol = (tid & 3) * 8;
            short8 sv;
#pragma unroll
            for (int j = 0; j < 8; j++) {
                float w = Bf[(size_t)(n0 + brow) * ldb + kb + bcol + j];
                if (!(w == w)) w = 0.f;
                sv[j] = (short)f2bits(clampf(w, -1e4f, 1e4f));
            }
            *(short8*)&Bs[brow][bcol] = sv;
        } else {
            int rbase = wave * 16;
            const short* gsrc = &Bg[(size_t)(n0 + rbase + lrow) * ldb + kb + lcol];
#if HAS_GLL
            gll16(gsrc, &Bs[rbase][0]);
#else
            *(short8*)&Bs[rbase + lrow][lcol] = *(const short8*)gsrc;
#endif
        }
        __syncthreads();
        short8 af[MI], bfr[2];
#pragma unroll
        for (int i = 0; i < MI; i++)
            af[i] = *(const short8*)&As[wm * (BM / 2) + i * 16 + row16][quad * 8];
#pragma unroll
        for (int j = 0; j < 2; j++)
            bfr[j] = *(const short8*)&Bs[wn * 32 + j * 16 + row16][quad * 8];
#pragma unroll
        for (int i = 0; i < MI; i++)
#pragma unroll
            for (int j = 0; j < 2; j++)
                acc[i][j] = __builtin_amdgcn_mfma_f32_16x16x32_bf16(af[i], bfr[j], acc[i][j], 0, 0, 0);
        __syncthreads();
    }

#pragma unroll
    for (int i = 0; i < MI; i++)
#pragma unroll
        for (int j = 0; j < 2; j++) {
            int mb = m0 + wm * (BM / 2) + i * 16 + quad * 4;
            int n = n0 + wn * 32 + j * 16 + row16;
            if (TRANSC) {
                ushort4v pack;
#pragma unroll
                for (int r = 0; r < 4; r++) {
                    int m = mb + r;
                    float v = acc[i][j][r];
                    if (EPI == 0) {
                        v = clampf(v + ldin(bias, n, fp32), -1e6f, 1e6f);
                    } else {   // EPI == 1
                        v = fminf(0.0625f * (expf(fminf(v - diag[m], 60.f)) + 1e-4f), 1e8f);
                    }
                    pack[r] = f2bits(v);
                }
                int blq = mb >> 12, tb = mb & 4095;
                *(ushort4v*)((unsigned short*)Cb +
                    (size_t)blq * CC * NTOKB + (size_t)n * NTOKB + tb) = pack;
            } else {
#pragma unroll
                for (int r = 0; r < 4; r++) {
                    int m = mb + r;
                    float v = acc[i][j][r];
                    if (EPI == 0) {
                        v = clampf(v + ldin(bias, n, fp32), -1e6f, 1e6f);
                        Cb[(size_t)m * ldc + n] = f2bf(v);
                    } else if (EPI == 1) {
                        v = fminf(0.0625f * (expf(fminf(v - diag[m], 60.f)) + 1e-4f), 1e8f);
                        Cb[(size_t)m * ldc + n] = f2bf(v);
                    } else if (EPI == 2) {
                        v += ldin(bias, n, fp32);
                        v = 0.5f * v * (1.f + erff(v * 0.70710678118654752f));
                        Cb[(size_t)m * ldc + n] = f2bf(v);
                    } else if (EPI == 3) {
                        v += ldin(bias, n, fp32);
                        size_t idx = (size_t)m * ldc + n;
                        v = clampf(v + bf2f(Cb[idx]), -1e6f, 1e6f);
                        Cb[idx] = f2bf(v);
                    } else if (EPI == 4) {
                        Cf[(size_t)z * MperZ + (size_t)m * ldc + n] = v;
                    } else if (EPI == 5) {
                        size_t mg = (size_t)bl * MperZ + m;
                        float addv = clampf(v * dinv[mg], -1e6f, 1e6f);
                        size_t idx = mg * ldc + n;
                        Cb[idx] = f2bf(bf2f(Cb[idx]) + addv);
                    }
                }
            }
        }
}

// PART[z=bl*8+ch][f][c] (fp32) -> CTX_T[bl][c][f] (bf16)
__global__ void reduce_ctx(const float* __restrict__ PART, bf16* __restrict__ CTXT) {
    int f = blockIdx.x;
    int bl = blockIdx.y;
    int c = threadIdx.x;
    float s = 0.f;
#pragma unroll
    for (int ch = 0; ch < 8; ch++)
        s += PART[(((size_t)bl * 8 + ch) * FF + f) * CC + c];
    s = clampf(s, -1e18f, 1e18f);
    CTXT[((size_t)bl * CC + c) * FF + f] = f2bf(s);
}

__global__ void colsum_t(const bf16* __restrict__ KPT, float* __restrict__ KSUM) {
    int bl = blockIdx.y;
    int f = blockIdx.x * 4 + (threadIdx.x >> 6);
    int lane = threadIdx.x & 63;
    const short* row = (const short*)KPT + ((size_t)bl * FF + f) * NTOKB;
    float s = 0.f;
    for (int i = lane * 8; i < NTOKB; i += 512) {
        short8 v = *(const short8*)&row[i];
#pragma unroll
        for (int j = 0; j < 8; j++) s += s2f(v[j]);
    }
    s = wave_sum(s);
    if (lane == 0) KSUM[(size_t)bl * FF + f] = s;
}

__global__ void dinv_v(const bf16* __restrict__ QP, const float* __restrict__ KSUM,
                       float* __restrict__ DINV) {
    int bl = blockIdx.y;
    int t = blockIdx.x * 4 + (threadIdx.x >> 6);
    int lane = threadIdx.x & 63;
    const short* row = (const short*)QP + ((size_t)bl * NTOKB + t) * FF;
    const float* ks = KSUM + (size_t)bl * FF;
    short4v u = *(const short4v*)&row[lane * 4];
    float s = 0.f;
#pragma unroll
    for (int j = 0; j < 4; j++) s += s2f(u[j]) * ks[lane * 4 + j];
    s = wave_sum(s);
    if (lane == 0) DINV[(size_t)bl * NTOKB + t] = fminf(1.f / fmaxf(s, 1e-30f), 1e6f);
}

// ============================================================================
extern "C" void kernel_launch(void* const* d_in, const int* in_sizes, int n_in,
                              void* d_out, int out_size, void* d_ws, size_t ws_size,
                              hipStream_t stream) {
    const void* x    = d_in[0];
    const void* proj = d_in[1];
    const void* wq   = d_in[2];
    const void* bq   = d_in[3];
    const void* wk   = d_in[4];
    const void* bk   = d_in[5];
    const void* wa   = d_in[6];
    const void* ba   = d_in[7];
    const void* g1   = d_in[8];
    const void* b1   = d_in[9];
    const void* g2   = d_in[10];
    const void* b2   = d_in[11];
    const void* w1   = d_in[12];
    const void* fb1  = d_in[13];
    const void* w2   = d_in[14];
    const void* fb2  = d_in[15];

    char* base = (char*)d_ws;
    const size_t MB = 1048576ull;
    const bool fast = ws_size >= 160 * MB;   // ws confirmed 256 MiB (R8 fillBuffer)

    if (fast) {
        // ---- full-batch layout (peak ~146 MiB) ----
        bf16* T    = (bf16*)base;                    // [0,16M)
        bf16* Hs   = (bf16*)(base + 16 * MB);        // [16,32M)  H -> QP -> H2
        bf16* Qs   = (bf16*)(base + 32 * MB);        // [32,48M)  Q -> KP_T
        bf16* Ks   = (bf16*)(base + 48 * MB);        // [48,64M)  K; then PART
        bf16* VT   = (bf16*)(base + 64 * MB);        // [64,80M)  V_T
        bf16* MID  = (bf16*)(base + 80 * MB);        // [80,144M) MLP hidden
        float* PART = (float*)(base + 48 * MB);      // 64*256*256 fp32 = 16.7M (K dead)
        char* sm = base + 144 * MB;
        int* MODE = (int*)sm;
        float* DIAGQ = (float*)(sm + 1024);          // NTOK
        float* DIAGK = DIAGQ + NTOK;
        float* DINV  = DIAGK + NTOK;
        float* KSUM  = DINV + NTOK;                  // BB*FF
        bf16* CTXT   = (bf16*)(sm + 2 * MB);         // BB*256*256 bf16 = 1M

        dim3 tb32(32, 8);
        detect_mode<<<1, 64, 0, stream>>>(x, MODE);
        transpose_in_z<<<dim3(NTOKB / 32, CC / 32, BB), tb32, 0, stream>>>(x, T, MODE);

        layernorm_v<<<NTOK / 4, 256, 0, stream>>>(T, g1, b1, Hs, MODE);
        // QKV: M=32768 N=256 K=256; grid (4, 256) = 1024 blocks
        mgemm<128, 0, false, true><<<dim3(4, 256, 1), 256, 0, stream>>>(
            Hs, 256, 0, wq, 256, 0, bq, nullptr, nullptr, Qs, 256,
            nullptr, 0, 256, 1, MODE);
        mgemm<128, 0, false, true><<<dim3(4, 256, 1), 256, 0, stream>>>(
            Hs, 256, 0, wk, 256, 0, bk, nullptr, nullptr, Ks, 256,
            nullptr, 0, 256, 1, MODE);
        mgemm<128, 0, true, true><<<dim3(4, 256, 1), 256, 0, stream>>>(
            Hs, 256, 0, wa, 256, 0, ba, nullptr, nullptr, VT, 0,
            nullptr, 0, 256, 1, MODE);
        rownorm_v<<<NTOK / 4, 256, 0, stream>>>(Qs, DIAGQ);
        rownorm_v<<<NTOK / 4, 256, 0, stream>>>(Ks, DIAGK);
        mgemm<128, 1, false, true><<<dim3(4, 256, 1), 256, 0, stream>>>(
            Qs, 256, 0, proj, 256, 0, nullptr, DIAGQ, nullptr, Hs, 256,
            nullptr, 0, 256, 1, MODE);
        mgemm<128, 1, true, true><<<dim3(4, 256, 1), 256, 0, stream>>>(
            Ks, 256, 0, proj, 256, 0, nullptr, DIAGK, nullptr, Qs, 0,
            nullptr, 0, 256, 1, MODE);
        bf16* QP  = Hs;
        bf16* KPT = Qs;
        colsum_t<<<dim3(FF / 4, BB), 256, 0, stream>>>(KPT, KSUM);
        dinv_v<<<dim3(NTOKB / 4, BB), 256, 0, stream>>>(QP, KSUM, DINV);
        // ctx: M=F=256, N=C=256, K=4096 split 8; z = 8 batches * 8 chunks
        mgemm<64, 4, false, false><<<dim3(4, 4, BB * 8), 256, 0, stream>>>(
            KPT, NTOKB, (long long)FF * NTOKB, VT, NTOKB, (long long)CC * NTOKB,
            nullptr, nullptr, nullptr, nullptr, CC,
            PART, FF * CC, 512, 8, MODE);
        reduce_ctx<<<dim3(FF, BB), 256, 0, stream>>>(PART, CTXT);
        // attnout: M=4096/batch, N=256, K=256; (4, 32, 8) = 1024 blocks
        mgemm<128, 5, false, false><<<dim3(4, 32, BB), 256, 0, stream>>>(
            QP, 256, (long long)NTOKB * FF, CTXT, FF, (long long)CC * FF,
            nullptr, nullptr, DINV, T, 256,
            nullptr, NTOKB, 256, 1, MODE);
        // MLP
        layernorm_v<<<NTOK / 4, 256, 0, stream>>>(T, g2, b2, Hs, MODE);
        mgemm<128, 2, false, true><<<dim3(16, 256, 1), 256, 0, stream>>>(
            Hs, 256, 0, w1, 256, 0, fb1, nullptr, nullptr, MID, 1024,
            nullptr, 0, 256, 1, MODE);
        mgemm<128, 3, false, true><<<dim3(4, 256, 1), 256, 0, stream>>>(
            MID, 1024, 0, w2, 1024, 0, fb2, nullptr, nullptr, T, 256,
            nullptr, 0, 1024, 1, MODE);
        transpose_out_z<<<dim3(CC / 32, NTOKB / 32, BB), tb32, 0, stream>>>(T, d_out, MODE);
        return;
    }

    // ================= FALLBACK: proven R5 per-batch path =================
    bf16* Tb   = (bf16*)(base);
    bf16* Hb   = (bf16*)(base + 2 * MB);
    bf16* Qb   = (bf16*)(base + 4 * MB);
    bf16* Kb   = (bf16*)(base + 6 * MB);
    bf16* Vb   = (bf16*)(base + 8 * MB);
    bf16* QPb  = (bf16*)(base + 2 * MB);
    bf16* KPb  = (bf16*)(base + 4 * MB);
    bf16* MIDb = (bf16*)(base + 2 * MB);
    bf16* H2b  = (bf16*)(base + 10 * MB);
    char* sm   = base + 12 * MB;
    int*   MODE  = (int*)sm;
    float* DIAGQ = (float*)(sm + 256);
    float* DIAGK = DIAGQ + NTOKB;
    float* DINV  = DIAGK + NTOKB;
    float* KSUM  = DINV + NTOKB;
    float* KPART = KSUM + FF;
    float* CTX   = KPART + 32 * FF;

    dim3 tb32(32, 8);
    dim3 tb16(16, 16);
    dim3 gq(CC / 32, NTOKB / 32);

    detect_mode<<<1, 64, 0, stream>>>(x, MODE);

    for (int b = 0; b < BB; b++) {
        size_t eoff = (size_t)b * CC * NTOKB;
        transpose_in_off<<<dim3(NTOKB / 32, CC / 32), tb32, 0, stream>>>(x, Tb, MODE, eoff);
        layernorm_k<<<NTOKB / 4, 256, 0, stream>>>(Tb, g1, b1, Hb, MODE);
        gemm_nt<0><<<gq, tb16, 0, stream>>>(Hb, wq, bq, nullptr, nullptr, Qb, NTOKB, CC, CC, MODE);
        gemm_nt<0><<<gq, tb16, 0, stream>>>(Hb, wk, bk, nullptr, nullptr, Kb, NTOKB, CC, CC, MODE);
        gemm_nt<0><<<gq, tb16, 0, stream>>>(Hb, wa, ba, nullptr, nullptr, Vb, NTOKB, CC, CC, MODE);
        rownorm_k<<<NTOKB / 4, 256, 0, stream>>>(Qb, DIAGQ);
        rownorm_k<<<NTOKB / 4, 256, 0, stream>>>(Kb, DIAGK);
        gemm_nt<1><<<gq, tb16, 0, stream>>>(Qb, proj, nullptr, DIAGQ, nullptr, QPb, NTOKB, FF, CC, MODE);
        gemm_nt<1><<<gq, tb16, 0, stream>>>(Kb, proj, nullptr, DIAGK, nullptr, KPb, NTOKB, FF, CC, MODE);
        colsum_k<<<32, 256, 0, stream>>>(KPb, KPART);
        ksum_reduce<<<1, 256, 0, stream>>>(KPART, KSUM);
        dinv_k<<<NTOKB / 4, 256, 0, stream>>>(QPb, KSUM, DINV);
        gemm_ctx_fb<<<dim3(CC / 32, FF / 32), tb16, 0, stream>>>(KPb, Vb, CTX);
        gemm_attnout_fb<<<gq, tb16, 0, stream>>>(QPb, CTX, DINV, Tb);
        layernorm_k<<<NTOKB / 4, 256, 0, stream>>>(Tb, g2, b2, H2b, MODE);
        gemm_nt<2><<<dim3(HIDDEN / 32, NTOKB / 32), tb16, 0, stream>>>(H2b, w1, fb1, nullptr, nullptr, MIDb, NTOKB, HIDDEN, CC, MODE);
        gemm_nt<3><<<gq, tb16, 0, stream>>>(MIDb, w2, fb2, nullptr, Tb, Tb, NTOKB, CC, HIDDEN, MODE);
        transpose_out_off<<<dim3(CC / 32, NTOKB / 32), tb32, 0, stream>>>(Tb, d_out, MODE, eoff);
    }
}